// Round 11
// baseline (3790.687 us; speedup 1.0000x reference)
//
#include <hip/hip_runtime.h>
#include <math.h>

namespace {
constexpr int kV = 12001;
constexpr int kE = 300;
constexpr int kEp = 320;   // padded K for i2h
constexpr int kR = 1024;
constexpr int kH = 512;
constexpr int kF = 2048;
constexpr int kB = 64;
constexpr int kT = 20;
constexpr int kL = 196;
}

typedef __attribute__((ext_vector_type(8))) short short8;
typedef __attribute__((ext_vector_type(4))) float f32x4;

__device__ __forceinline__ unsigned short f2bf(float f) {
    unsigned u = __builtin_bit_cast(unsigned, f);
    u = (u + 0x7fffu + ((u >> 16) & 1u)) >> 16;
    return (unsigned short)u;
}
__device__ __forceinline__ float bf2f(unsigned short h) {
    unsigned u = ((unsigned)h) << 16;
    return __builtin_bit_cast(float, u);
}
__device__ __forceinline__ float fast_tanh(float x) {
    x = fminf(15.f, fmaxf(-15.f, x));
    const float e = __expf(2.f * x);
    return (e - 1.f) / (e + 1.f);
}
__device__ __forceinline__ float fast_sig(float x) {
    return 1.f / (1.f + __expf(-x));
}

// ---------------------------------------------------------------------------
// fp32 -> bf16 (n4 = count/4)
// ---------------------------------------------------------------------------
__global__ __launch_bounds__(256)
void conv_hi_kernel(const float* __restrict__ in, unsigned short* __restrict__ out, int n4)
{
    for (int i = blockIdx.x * 256 + threadIdx.x; i < n4; i += gridDim.x * 256) {
        const float4 v = ((const float4*)in)[i];
        ushort4 o;
        o.x = f2bf(v.x); o.y = f2bf(v.y); o.z = f2bf(v.z); o.w = f2bf(v.w);
        ((ushort4*)out)[i] = o;
    }
}

// fp32 rows of 300 -> bf16 rows padded to 320 (pads pre-zeroed by memset)
__global__ __launch_bounds__(256)
void conv_pad300_kernel(const float* __restrict__ in, unsigned short* __restrict__ out, int rows)
{
    const int total = rows * 75;   // 75 float4 per row
    for (int i = blockIdx.x * 256 + threadIdx.x; i < total; i += gridDim.x * 256) {
        const int r = i / 75, c = i - r * 75;
        const float4 v = *(const float4*)(in + (size_t)r * kE + c * 4);
        ushort4 o;
        o.x = f2bf(v.x); o.y = f2bf(v.y); o.z = f2bf(v.z); o.w = f2bf(v.w);
        *(ushort4*)(out + (size_t)r * kEp + c * 4) = o;
    }
}

// ---------------------------------------------------------------------------
// Pure-bf16 MFMA GEMM: C[m,n] = sum_k A[row(m),k]*W[n,k] + bias[n]
// 128x128 tile, BK=32, 4 waves, 1 MFMA/term. M%128==0, K%32==0; N edge ok.
// ---------------------------------------------------------------------------
template<bool OUT_BF16, bool GATHER>
__global__ __launch_bounds__(256)
void gemm_bf_kernel(const unsigned short* __restrict__ Ah, int lda,
                    const unsigned short* __restrict__ Wh, int ldw,
                    const float* __restrict__ bias,
                    void* __restrict__ Cp, int ldc,
                    int M, int N, int K,
                    const int* __restrict__ ridx)
{
    __shared__ unsigned short sA[128][40];
    __shared__ unsigned short sW[128][40];
    const int tid = threadIdx.x;
    const int m0 = blockIdx.y * 128;
    const int n0 = blockIdx.x * 128;
    const int wave = tid >> 6, lane = tid & 63;
    const int wm = wave >> 1, wn = wave & 1;
    const int lrow = lane & 15, lkg = lane >> 4;

    f32x4 acc[4][4];
    #pragma unroll
    for (int mi = 0; mi < 4; ++mi)
        #pragma unroll
        for (int ni = 0; ni < 4; ++ni)
            acc[mi][ni] = (f32x4){0.f, 0.f, 0.f, 0.f};

    for (int k0 = 0; k0 < K; k0 += 32) {
        for (int g = tid; g < 512; g += 256) {
            const int r = g >> 2, q = g & 3;
            const int k = k0 + q * 8;
            const int m = m0 + r;
            const int row = GATHER ? ridx[m] : m;
            *(short8*)&sA[r][q * 8] = *(const short8*)(Ah + (size_t)row * lda + k);
        }
        for (int g = tid; g < 512; g += 256) {
            const int r = g >> 2, q = g & 3;
            const int k = k0 + q * 8;
            const int n = n0 + r;
            short8 v = (short8){0,0,0,0,0,0,0,0};
            if (n < N) v = *(const short8*)(Wh + (size_t)n * ldw + k);
            *(short8*)&sW[r][q * 8] = v;
        }
        __syncthreads();

        short8 af[4], wf[4];
        #pragma unroll
        for (int mi = 0; mi < 4; ++mi)
            af[mi] = *(const short8*)&sA[wm * 64 + mi * 16 + lrow][lkg * 8];
        #pragma unroll
        for (int ni = 0; ni < 4; ++ni)
            wf[ni] = *(const short8*)&sW[wn * 64 + ni * 16 + lrow][lkg * 8];
        #pragma unroll
        for (int mi = 0; mi < 4; ++mi)
            #pragma unroll
            for (int ni = 0; ni < 4; ++ni)
                acc[mi][ni] = __builtin_amdgcn_mfma_f32_16x16x32_bf16(af[mi], wf[ni], acc[mi][ni], 0, 0, 0);
        __syncthreads();
    }

    // epilogue: row = (lane>>4)*4 + reg, col = lane&15 (m89-verified layout)
    #pragma unroll
    for (int mi = 0; mi < 4; ++mi) {
        const int mbase = m0 + wm * 64 + mi * 16 + lkg * 4;
        #pragma unroll
        for (int ni = 0; ni < 4; ++ni) {
            const int n = n0 + wn * 64 + ni * 16 + lrow;
            if (n >= N) continue;
            const float bb = bias ? bias[n] : 0.f;
            #pragma unroll
            for (int r = 0; r < 4; ++r) {
                const int m = mbase + r;
                const float v = acc[mi][ni][r] + bb;
                if (OUT_BF16) ((unsigned short*)Cp)[(size_t)m * ldc + n] = f2bf(v);
                else          ((float*)Cp)[(size_t)m * ldc + n] = v;
            }
        }
    }
}

// ---------------------------------------------------------------------------
// att_h: grid (64 jg, 8 bg). Block stages 8 w-rows + 8 h-rows in LDS,
// computes the 8x8 (j,b) dot tile. Weight traffic 16 MB/step. (R9-verified)
// ---------------------------------------------------------------------------
__global__ __launch_bounds__(256)
void att_h_kernel(const float* __restrict__ h_in,
                  const float* __restrict__ w,
                  const float* __restrict__ bias,
                  float* __restrict__ att_h)
{
    __shared__ float wl[8][1024];
    __shared__ float hl[8][1024];
    const int jg = blockIdx.x, bg = blockIdx.y;
    const int tid = threadIdx.x;
    for (int i = tid; i < 2048; i += 256) {
        const int r = i >> 8, c4 = i & 255;
        ((float4*)&wl[r][0])[c4] = ((const float4*)(w    + (size_t)(jg * 8 + r) * kR))[c4];
        ((float4*)&hl[r][0])[c4] = ((const float4*)(h_in + (size_t)(bg * 8 + r) * kR))[c4];
    }
    __syncthreads();
    const int wave = tid >> 6, lane = tid & 63;
    #pragma unroll
    for (int i = 0; i < 16; ++i) {
        const int p = wave * 16 + i;
        const int j = p >> 3, b = p & 7;
        float a = 0.f;
        #pragma unroll
        for (int it = 0; it < 4; ++it) {
            const float4 wv = ((const float4*)&wl[j][0])[it * 64 + lane];
            const float4 hv = ((const float4*)&hl[b][0])[it * 64 + lane];
            a += wv.x * hv.x + wv.y * hv.y + wv.z * hv.z + wv.w * hv.w;
        }
        #pragma unroll
        for (int off = 32; off; off >>= 1) a += __shfl_xor(a, off, 64);
        if (lane == 0) att_h[(bg * 8 + b) * kH + jg * 8 + j] = a + bias[jg * 8 + j];
    }
}

// ---------------------------------------------------------------------------
// K2: e + softmax (redundant per fc) + readout quarter. grid (4 fc, 64 b).
// ---------------------------------------------------------------------------
__global__ __launch_bounds__(256)
void att_es_readout_kernel(const float* __restrict__ att_h,
                           const unsigned short* __restrict__ p_att_bf,
                           const float* __restrict__ alpha_w,
                           const unsigned short* __restrict__ af_bf,
                           unsigned short* __restrict__ att_res_bf)
{
    const int fc = blockIdx.x, b = blockIdx.y;
    const int tid = threadIdx.x;
    const int wave = tid >> 6, lane = tid & 63;
    __shared__ float ahT[8][64];
    __shared__ float awT[8][64];
    __shared__ float esm[kL];
    __shared__ float wsm[kL];
    __shared__ float red2[2];

    for (int i = tid; i < kH; i += 256) {
        ahT[i & 7][i >> 3] = att_h[b * kH + i];
        awT[i & 7][i >> 3] = alpha_w[i];
    }
    __syncthreads();

    // e: 4 waves, wave handles l = wave, wave+4, ...  (h = lane*8 + j)
    for (int l = wave; l < kL; l += 4) {
        const short8 pv = *(const short8*)(p_att_bf + ((size_t)b * kL + l) * kH + lane * 8);
        float a = 0.f;
        #pragma unroll
        for (int j = 0; j < 8; ++j)
            a += fast_tanh(bf2f(((const unsigned short*)&pv)[j]) + ahT[j][lane]) * awT[j][lane];
        #pragma unroll
        for (int off = 32; off; off >>= 1) a += __shfl_xor(a, off, 64);
        if (lane == 0) esm[l] = a;
    }
    __syncthreads();

    if (wave == 0) {
        float m = -1e30f;
        for (int l = lane; l < kL; l += 64) m = fmaxf(m, esm[l]);
        #pragma unroll
        for (int off = 32; off; off >>= 1) m = fmaxf(m, __shfl_xor(m, off, 64));
        float ssum = 0.f;
        for (int l = lane; l < kL; l += 64) ssum += __expf(esm[l] - m);
        #pragma unroll
        for (int off = 32; off; off >>= 1) ssum += __shfl_xor(ssum, off, 64);
        if (lane == 0) { red2[0] = m; red2[1] = 1.f / ssum; }
    }
    __syncthreads();
    if (tid < kL) wsm[tid] = __expf(esm[tid] - red2[0]) * red2[1];
    __syncthreads();

    // readout quarter: thread owns 2 f-cols (coalesced 1 KB/row per block)
    const int col = fc * 512 + tid * 2;
    float a0 = 0.f, a1 = 0.f;
    const unsigned short* base = af_bf + (size_t)b * kL * kF + col;
    #pragma unroll 4
    for (int l = 0; l < kL; ++l) {
        const ushort2 v = *(const ushort2*)(base + (size_t)l * kF);
        const float wl = wsm[l];
        a0 += wl * bf2f(v.x);
        a1 += wl * bf2f(v.y);
    }
    ushort2 o;
    o.x = f2bf(a0); o.y = f2bf(a1);
    *(ushort2*)(att_res_bf + (size_t)b * kF + col) = o;
}

// ---------------------------------------------------------------------------
// Fused LSTM step (h2h + a2c(bf16 att_res) + i2h_pre + gates).
// 512 blocks x 2 r-cols. Writes h_out fp32 and h_all bf16.
// ---------------------------------------------------------------------------
__global__ __launch_bounds__(256)
void lstm_fused_kernel(const float* __restrict__ h_in,
                       const unsigned short* __restrict__ ares_bf,
                       const float* __restrict__ i2h_pre,
                       const float* __restrict__ h2h_w,
                       const float* __restrict__ h2h_b,
                       const float* __restrict__ a2c_w,
                       const float* __restrict__ a2c_b,
                       float* __restrict__ h_out,
                       float* __restrict__ cbuf,
                       unsigned short* __restrict__ h_all_bf,
                       int t)
{
    __shared__ float hs[64][68];
    __shared__ float ws[10][68];
    const int blk = blockIdx.x;
    const int tid = threadIdx.x;
    const int bq = tid >> 4, s = tid & 15;
    const int rc0 = blk * 2;
    const int kk = s * 4;
    float acc[4][10];
    #pragma unroll
    for (int i = 0; i < 4; ++i)
        #pragma unroll
        for (int rw = 0; rw < 10; ++rw) acc[i][rw] = 0.f;

    for (int k0 = 0; k0 < kR; k0 += 64) {
        for (int i = tid; i < 1024; i += 256) {
            const int bl = i >> 4, c4 = (i & 15) * 4;
            *(float4*)&hs[bl][c4] = *(const float4*)&h_in[bl * kR + k0 + c4];
        }
        for (int i = tid; i < 160; i += 256) {
            const int rw = i >> 4, c4 = (i & 15) * 4;
            *(float4*)&ws[rw][c4] =
                *(const float4*)&h2h_w[(size_t)((rw >> 1) * kR + rc0 + (rw & 1)) * kR + k0 + c4];
        }
        __syncthreads();
        float4 hv[4];
        #pragma unroll
        for (int i = 0; i < 4; ++i) hv[i] = *(const float4*)&hs[bq * 4 + i][kk];
        #pragma unroll
        for (int rw = 0; rw < 10; ++rw) {
            const float4 wv = *(const float4*)&ws[rw][kk];
            #pragma unroll
            for (int i = 0; i < 4; ++i)
                acc[i][rw] += hv[i].x * wv.x + hv[i].y * wv.y + hv[i].z * wv.z + hv[i].w * wv.w;
        }
        __syncthreads();
    }
    for (int k0 = 0; k0 < kF; k0 += 64) {
        for (int i = tid; i < 1024; i += 256) {
            const int bl = i >> 4, c4 = (i & 15) * 4;
            const ushort4 v = *(const ushort4*)&ares_bf[(size_t)bl * kF + k0 + c4];
            *(float4*)&hs[bl][c4] = make_float4(bf2f(v.x), bf2f(v.y), bf2f(v.z), bf2f(v.w));
        }
        for (int i = tid; i < 64; i += 256) {
            const int rw = i >> 4, c4 = (i & 15) * 4;
            *(float4*)&ws[rw][c4] =
                *(const float4*)&a2c_w[(size_t)((rw >> 1) * kR + rc0 + (rw & 1)) * kF + k0 + c4];
        }
        __syncthreads();
        float4 av[4];
        #pragma unroll
        for (int i = 0; i < 4; ++i) av[i] = *(const float4*)&hs[bq * 4 + i][kk];
        #pragma unroll
        for (int rw = 0; rw < 4; ++rw) {
            const float4 wv = *(const float4*)&ws[rw][kk];
            #pragma unroll
            for (int i = 0; i < 4; ++i)
                acc[i][6 + rw] += av[i].x * wv.x + av[i].y * wv.y + av[i].z * wv.z + av[i].w * wv.w;
        }
        __syncthreads();
    }
    #pragma unroll
    for (int i = 0; i < 4; ++i)
        #pragma unroll
        for (int rw = 0; rw < 10; ++rw) {
            float v = acc[i][rw];
            v += __shfl_xor(v, 1, 64); v += __shfl_xor(v, 2, 64);
            v += __shfl_xor(v, 4, 64); v += __shfl_xor(v, 8, 64);
            acc[i][rw] = v;
        }
    if (s == 0) {
        #pragma unroll
        for (int i = 0; i < 4; ++i) {
            const int b = bq * 4 + i;
            const float* ib = i2h_pre + (size_t)(b * kT + t) * (5 * kR);
            #pragma unroll
            for (int rr = 0; rr < 2; ++rr) {
                const int r = rc0 + rr;
                const float S0 = acc[i][0 + rr] + ib[r]          + h2h_b[r];
                const float S1 = acc[i][2 + rr] + ib[kR + r]     + h2h_b[kR + r];
                const float S2 = acc[i][4 + rr] + ib[2 * kR + r] + h2h_b[2 * kR + r];
                const float S3 = acc[i][6 + rr] + ib[3 * kR + r] + h2h_b[3 * kR + r] + a2c_b[r];
                const float S4 = acc[i][8 + rr] + ib[4 * kR + r] + h2h_b[4 * kR + r] + a2c_b[kR + r];
                const float ing = fast_sig(S0);
                const float fg  = fast_sig(S1);
                const float og  = fast_sig(S2);
                const float gg  = fmaxf(S3, S4);
                const float nc  = fg * cbuf[b * kR + r] + ing * gg;
                const float nh  = og * fast_tanh(nc);
                cbuf[b * kR + r] = nc;
                h_out[b * kR + r] = nh;
                h_all_bf[(size_t)(b * kT + t) * kR + r] = f2bf(nh);
            }
        }
    }
}

// ---------------------------------------------------------------------------
// in-place log_softmax over V; one block per row. Online max/sum.
// ---------------------------------------------------------------------------
__global__ __launch_bounds__(256)
void log_softmax_kernel(float* __restrict__ out)
{
    __shared__ float mred[256];
    __shared__ float sred[256];
    const int tid = threadIdx.x;
    float* row = out + (size_t)blockIdx.x * kV;

    float m = -1e30f, s = 0.f;
    for (int v = tid; v < kV; v += 256) {
        const float x = row[v];
        if (x > m) { s = s * __expf(m - x) + 1.f; m = x; }
        else        s += __expf(x - m);
    }
    mred[tid] = m; sred[tid] = s; __syncthreads();
    for (int st = 128; st > 0; st >>= 1) {
        if (tid < st) {
            const float m2 = mred[tid + st], s2 = sred[tid + st];
            const float M = fmaxf(mred[tid], m2);
            sred[tid] = sred[tid] * __expf(mred[tid] - M) + s2 * __expf(m2 - M);
            mred[tid] = M;
        }
        __syncthreads();
    }
    const float ls = mred[0] + logf(sred[0]);
    for (int v = tid; v < kV; v += 256) row[v] -= ls;
}

extern "C" void kernel_launch(void* const* d_in, const int* in_sizes, int n_in,
                              void* d_out, int out_size, void* d_ws, size_t ws_size,
                              hipStream_t stream)
{
    const int*   seq       = (const int*)  d_in[0];
    const float* att_feats = (const float*)d_in[1];
    const float* embed_w   = (const float*)d_in[2];
    const float* ctx2att_w = (const float*)d_in[3];
    const float* ctx2att_b = (const float*)d_in[4];
    const float* h2att_w   = (const float*)d_in[5];
    const float* h2att_b   = (const float*)d_in[6];
    const float* alpha_w   = (const float*)d_in[7];
    const float* i2h_w     = (const float*)d_in[9];
    const float* i2h_b     = (const float*)d_in[10];
    const float* h2h_w     = (const float*)d_in[11];
    const float* h2h_b     = (const float*)d_in[12];
    const float* a2c_w     = (const float*)d_in[13];
    const float* a2c_b     = (const float*)d_in[14];
    const float* logit_w   = (const float*)d_in[15];
    const float* logit_b   = (const float*)d_in[16];
    float* out = (float*)d_out;

    float* ws = (float*)d_ws;
    size_t off = 0;
    auto alloc = [&](size_t nf) { float* p = ws + off; off += (nf + 3) & ~(size_t)3; return p; };

    unsigned short* af_bf      = (unsigned short*)alloc((size_t)kB * kL * kF / 2);  // 51 MB
    unsigned short* p_att_bf   = (unsigned short*)alloc((size_t)kB * kL * kH / 2);  // 12.8 MB
    unsigned short* ctx_hi     = (unsigned short*)alloc((size_t)kH * kF / 2);
    unsigned short* logit_hi   = (unsigned short*)alloc((size_t)kV * kR / 2);
    unsigned short* embed_bf   = (unsigned short*)alloc((size_t)kV * kEp / 2);
    unsigned short* i2h_bf     = (unsigned short*)alloc((size_t)5 * kR * kEp / 2);
    unsigned short* h_all_bf   = (unsigned short*)alloc((size_t)kB * kT * kR / 2);
    unsigned short* att_res_bf = (unsigned short*)alloc((size_t)kB * kF / 2);
    float* i2h_pre = alloc((size_t)kB * kT * 5 * kR);   // 26 MB
    float* att_h   = alloc((size_t)kB * kH);
    float* h0      = alloc((size_t)kB * kR);
    float* h1      = alloc((size_t)kB * kR);
    float* cbuf    = alloc((size_t)kB * kR);

    hipMemsetAsync(h0,   0, (size_t)kB * kR * sizeof(float), stream);
    hipMemsetAsync(cbuf, 0, (size_t)kB * kR * sizeof(float), stream);
    hipMemsetAsync(embed_bf, 0, (size_t)kV * kEp * sizeof(unsigned short), stream);
    hipMemsetAsync(i2h_bf,   0, (size_t)5 * kR * kEp * sizeof(unsigned short), stream);

    // one-time conversions
    conv_hi_kernel<<<2048, 256, 0, stream>>>(att_feats, af_bf, kB * kL * kF / 4);
    conv_hi_kernel<<<512, 256, 0, stream>>>(ctx2att_w, ctx_hi, kH * kF / 4);
    conv_hi_kernel<<<2048, 256, 0, stream>>>(logit_w, logit_hi, kV * kR / 4);
    conv_pad300_kernel<<<1024, 256, 0, stream>>>(embed_w, embed_bf, kV);
    conv_pad300_kernel<<<512, 256, 0, stream>>>(i2h_w, i2h_bf, 5 * kR);

    // p_att = att_feats @ ctx2att_w.T + b -> bf16   (12544 x 512, K=2048)
    gemm_bf_kernel<true, false><<<dim3(kH / 128, kB * kL / 128), 256, 0, stream>>>(
        af_bf, kF, ctx_hi, kF, ctx2att_b, p_att_bf, kH, kB * kL, kH, kF, nullptr);

    // i2h_pre = embed[seq] @ i2h_w.T + b   (1280 x 5120, K=320 padded)
    gemm_bf_kernel<false, true><<<dim3(5 * kR / 128, kB * kT / 128), 256, 0, stream>>>(
        embed_bf, kEp, i2h_bf, kEp, i2h_b, i2h_pre, 5 * kR, kB * kT, 5 * kR, kEp, seq);

    // 20-step recurrence: 3 launches per step
    float* hin = h0;
    float* hout = h1;
    for (int t = 0; t < kT; ++t) {
        att_h_kernel<<<dim3(64, 8), 256, 0, stream>>>(hin, h2att_w, h2att_b, att_h);
        att_es_readout_kernel<<<dim3(4, kB), 256, 0, stream>>>(
            att_h, p_att_bf, alpha_w, af_bf, att_res_bf);
        lstm_fused_kernel<<<dim3(512), 256, 0, stream>>>(
            hin, att_res_bf, i2h_pre, h2h_w, h2h_b, a2c_w, a2c_b,
            hout, cbuf, h_all_bf, t);
        float* tmp = hin; hin = hout; hout = tmp;
    }

    // logits = h_all @ logit_w.T + b -> out fp32  (1280 x 12001, K=1024)
    gemm_bf_kernel<false, false><<<dim3((kV + 127) / 128, kB * kT / 128), 256, 0, stream>>>(
        h_all_bf, kR, logit_hi, kR, logit_b, out, kV, kB * kT, kV, kR, nullptr);

    log_softmax_kernel<<<dim3(kB * kT), 256, 0, stream>>>(out);
}

// Round 12
// 2089.535 us; speedup vs baseline: 1.8141x; 1.8141x over previous
//
#include <hip/hip_runtime.h>
#include <math.h>

namespace {
constexpr int kV = 12001;
constexpr int kE = 300;
constexpr int kEp = 320;   // padded K for i2h
constexpr int kR = 1024;
constexpr int kH = 512;
constexpr int kF = 2048;
constexpr int kB = 64;
constexpr int kT = 20;
constexpr int kL = 196;
constexpr int kNcat = 5 * kR + kH;   // 5632: [h2h | h2att]
}

typedef __attribute__((ext_vector_type(8))) short short8;
typedef __attribute__((ext_vector_type(4))) float f32x4;

__device__ __forceinline__ unsigned short f2bf(float f) {
    unsigned u = __builtin_bit_cast(unsigned, f);
    u = (u + 0x7fffu + ((u >> 16) & 1u)) >> 16;
    return (unsigned short)u;
}
__device__ __forceinline__ float bf2f(unsigned short h) {
    unsigned u = ((unsigned)h) << 16;
    return __builtin_bit_cast(float, u);
}
__device__ __forceinline__ float fast_tanh(float x) {
    x = fminf(15.f, fmaxf(-15.f, x));
    const float e = __expf(2.f * x);
    return (e - 1.f) / (e + 1.f);
}
__device__ __forceinline__ float fast_sig(float x) {
    return 1.f / (1.f + __expf(-x));
}

// ---------------------------------------------------------------------------
// fp32 -> bf16 (n4 = count/4)
// ---------------------------------------------------------------------------
__global__ __launch_bounds__(256)
void conv_hi_kernel(const float* __restrict__ in, unsigned short* __restrict__ out, int n4)
{
    for (int i = blockIdx.x * 256 + threadIdx.x; i < n4; i += gridDim.x * 256) {
        const float4 v = ((const float4*)in)[i];
        ushort4 o;
        o.x = f2bf(v.x); o.y = f2bf(v.y); o.z = f2bf(v.z); o.w = f2bf(v.w);
        ((ushort4*)out)[i] = o;
    }
}

// fp32 rows of 300 -> bf16 rows padded to 320 (pads pre-zeroed by memset)
__global__ __launch_bounds__(256)
void conv_pad300_kernel(const float* __restrict__ in, unsigned short* __restrict__ out, int rows)
{
    const int total = rows * 75;
    for (int i = blockIdx.x * 256 + threadIdx.x; i < total; i += gridDim.x * 256) {
        const int r = i / 75, c = i - r * 75;
        const float4 v = *(const float4*)(in + (size_t)r * kE + c * 4);
        ushort4 o;
        o.x = f2bf(v.x); o.y = f2bf(v.y); o.z = f2bf(v.z); o.w = f2bf(v.w);
        *(ushort4*)(out + (size_t)r * kEp + c * 4) = o;
    }
}

// ---------------------------------------------------------------------------
// Pure-bf16 MFMA GEMM (128x128 tile): C = A[row(m)] @ W.T + bias
// ---------------------------------------------------------------------------
template<bool OUT_BF16, bool GATHER>
__global__ __launch_bounds__(256)
void gemm_bf_kernel(const unsigned short* __restrict__ Ah, int lda,
                    const unsigned short* __restrict__ Wh, int ldw,
                    const float* __restrict__ bias,
                    void* __restrict__ Cp, int ldc,
                    int M, int N, int K,
                    const int* __restrict__ ridx)
{
    __shared__ unsigned short sA[128][40];
    __shared__ unsigned short sW[128][40];
    const int tid = threadIdx.x;
    const int m0 = blockIdx.y * 128;
    const int n0 = blockIdx.x * 128;
    const int wave = tid >> 6, lane = tid & 63;
    const int wm = wave >> 1, wn = wave & 1;
    const int lrow = lane & 15, lkg = lane >> 4;

    f32x4 acc[4][4];
    #pragma unroll
    for (int mi = 0; mi < 4; ++mi)
        #pragma unroll
        for (int ni = 0; ni < 4; ++ni)
            acc[mi][ni] = (f32x4){0.f, 0.f, 0.f, 0.f};

    for (int k0 = 0; k0 < K; k0 += 32) {
        for (int g = tid; g < 512; g += 256) {
            const int r = g >> 2, q = g & 3;
            const int k = k0 + q * 8;
            const int m = m0 + r;
            const int row = GATHER ? ridx[m] : m;
            *(short8*)&sA[r][q * 8] = *(const short8*)(Ah + (size_t)row * lda + k);
        }
        for (int g = tid; g < 512; g += 256) {
            const int r = g >> 2, q = g & 3;
            const int k = k0 + q * 8;
            const int n = n0 + r;
            short8 v = (short8){0,0,0,0,0,0,0,0};
            if (n < N) v = *(const short8*)(Wh + (size_t)n * ldw + k);
            *(short8*)&sW[r][q * 8] = v;
        }
        __syncthreads();

        short8 af[4], wf[4];
        #pragma unroll
        for (int mi = 0; mi < 4; ++mi)
            af[mi] = *(const short8*)&sA[wm * 64 + mi * 16 + lrow][lkg * 8];
        #pragma unroll
        for (int ni = 0; ni < 4; ++ni)
            wf[ni] = *(const short8*)&sW[wn * 64 + ni * 16 + lrow][lkg * 8];
        #pragma unroll
        for (int mi = 0; mi < 4; ++mi)
            #pragma unroll
            for (int ni = 0; ni < 4; ++ni)
                acc[mi][ni] = __builtin_amdgcn_mfma_f32_16x16x32_bf16(af[mi], wf[ni], acc[mi][ni], 0, 0, 0);
        __syncthreads();
    }

    #pragma unroll
    for (int mi = 0; mi < 4; ++mi) {
        const int mbase = m0 + wm * 64 + mi * 16 + lkg * 4;
        #pragma unroll
        for (int ni = 0; ni < 4; ++ni) {
            const int n = n0 + wn * 64 + ni * 16 + lrow;
            if (n >= N) continue;
            const float bb = bias ? bias[n] : 0.f;
            #pragma unroll
            for (int r = 0; r < 4; ++r) {
                const int m = mbase + r;
                const float v = acc[mi][ni][r] + bb;
                if (OUT_BF16) ((unsigned short*)Cp)[(size_t)m * ldc + n] = f2bf(v);
                else          ((float*)Cp)[(size_t)m * ldc + n] = v;
            }
        }
    }
}

// ---------------------------------------------------------------------------
// Small-M sums GEMM: part[ks][64][N] = A(64 x Ktot) @ W(N x Ktot).T  (K-split)
// BM=64, BN=64, BK=32. grid (N/64, ksplit). Kblk = Ktot/ksplit.
// ---------------------------------------------------------------------------
__global__ __launch_bounds__(256)
void gemm_sums_kernel(const unsigned short* __restrict__ A, int lda,
                      const unsigned short* __restrict__ W, int ldw,
                      float* __restrict__ part, int N, int Kblk)
{
    __shared__ unsigned short sA[64][40];
    __shared__ unsigned short sW[64][40];
    const int tid = threadIdx.x;
    const int n0 = blockIdx.x * 64;
    const int ks = blockIdx.y;
    const int kbeg = ks * Kblk;
    const int wave = tid >> 6, lane = tid & 63;
    const int lrow = lane & 15, lkg = lane >> 4;

    f32x4 acc[4];
    #pragma unroll
    for (int mi = 0; mi < 4; ++mi) acc[mi] = (f32x4){0.f, 0.f, 0.f, 0.f};

    const int r = tid >> 2, q = tid & 3;
    for (int k0 = kbeg; k0 < kbeg + Kblk; k0 += 32) {
        *(short8*)&sA[r][q * 8] = *(const short8*)(A + (size_t)r * lda + k0 + q * 8);
        *(short8*)&sW[r][q * 8] = *(const short8*)(W + (size_t)(n0 + r) * ldw + k0 + q * 8);
        __syncthreads();
        const short8 wf = *(const short8*)&sW[wave * 16 + lrow][lkg * 8];
        #pragma unroll
        for (int mi = 0; mi < 4; ++mi) {
            const short8 af = *(const short8*)&sA[mi * 16 + lrow][lkg * 8];
            acc[mi] = __builtin_amdgcn_mfma_f32_16x16x32_bf16(af, wf, acc[mi], 0, 0, 0);
        }
        __syncthreads();
    }

    float* po = part + (size_t)ks * 64 * N;
    const int n = n0 + wave * 16 + lrow;
    #pragma unroll
    for (int mi = 0; mi < 4; ++mi)
        #pragma unroll
        for (int rr = 0; rr < 4; ++rr)
            po[(size_t)(mi * 16 + lkg * 4 + rr) * N + n] = acc[mi][rr];
}

// ---------------------------------------------------------------------------
// e + softmax (redundant per fc) + readout quarter. grid (4 fc, 64 b).
// att_h read from part56 cols [5120, 5632) + bias.
// ---------------------------------------------------------------------------
__global__ __launch_bounds__(256)
void att_es_readout_kernel(const float* __restrict__ part56,
                           const float* __restrict__ h2att_b,
                           const unsigned short* __restrict__ p_att_bf,
                           const float* __restrict__ alpha_w,
                           const unsigned short* __restrict__ af_bf,
                           unsigned short* __restrict__ att_res_bf)
{
    const int fc = blockIdx.x, b = blockIdx.y;
    const int tid = threadIdx.x;
    const int wave = tid >> 6, lane = tid & 63;
    __shared__ float ahT[8][64];
    __shared__ float awT[8][64];
    __shared__ float esm[kL];
    __shared__ float wsm[kL];
    __shared__ float red2[2];

    for (int i = tid; i < kH; i += 256) {
        const size_t base = (size_t)b * kNcat + 5 * kR + i;
        ahT[i & 7][i >> 3] = part56[base] + part56[(size_t)64 * kNcat + base] + h2att_b[i];
        awT[i & 7][i >> 3] = alpha_w[i];
    }
    __syncthreads();

    for (int l = wave; l < kL; l += 4) {
        const short8 pv = *(const short8*)(p_att_bf + ((size_t)b * kL + l) * kH + lane * 8);
        float a = 0.f;
        #pragma unroll
        for (int j = 0; j < 8; ++j)
            a += fast_tanh(bf2f(((const unsigned short*)&pv)[j]) + ahT[j][lane]) * awT[j][lane];
        #pragma unroll
        for (int off = 32; off; off >>= 1) a += __shfl_xor(a, off, 64);
        if (lane == 0) esm[l] = a;
    }
    __syncthreads();

    if (wave == 0) {
        float m = -1e30f;
        for (int l = lane; l < kL; l += 64) m = fmaxf(m, esm[l]);
        #pragma unroll
        for (int off = 32; off; off >>= 1) m = fmaxf(m, __shfl_xor(m, off, 64));
        float ssum = 0.f;
        for (int l = lane; l < kL; l += 64) ssum += __expf(esm[l] - m);
        #pragma unroll
        for (int off = 32; off; off >>= 1) ssum += __shfl_xor(ssum, off, 64);
        if (lane == 0) { red2[0] = m; red2[1] = 1.f / ssum; }
    }
    __syncthreads();
    if (tid < kL) wsm[tid] = __expf(esm[tid] - red2[0]) * red2[1];
    __syncthreads();

    const int col = fc * 512 + tid * 2;
    float a0 = 0.f, a1 = 0.f;
    const unsigned short* base = af_bf + (size_t)b * kL * kF + col;
    #pragma unroll 4
    for (int l = 0; l < kL; ++l) {
        const ushort2 v = *(const ushort2*)(base + (size_t)l * kF);
        const float wl = wsm[l];
        a0 += wl * bf2f(v.x);
        a1 += wl * bf2f(v.y);
    }
    ushort2 o;
    o.x = f2bf(a0); o.y = f2bf(a1);
    *(ushort2*)(att_res_bf + (size_t)b * kF + col) = o;
}

// ---------------------------------------------------------------------------
// Gates: fold part56 + part_a2c + i2h_pre + biases -> c, h_all_bf[t].
// grid 256 blocks x 256 thr; thread owns one (b, r).
// ---------------------------------------------------------------------------
__global__ __launch_bounds__(256)
void gates_kernel(const float* __restrict__ part56,
                  const float* __restrict__ pa2c,
                  const float* __restrict__ i2h_pre,
                  const float* __restrict__ h2h_b,
                  const float* __restrict__ a2c_b,
                  float* __restrict__ cbuf,
                  unsigned short* __restrict__ h_all_bf,
                  int t)
{
    const int idx = blockIdx.x * 256 + threadIdx.x;
    const int b = idx >> 10, r = idx & 1023;
    const float* p0 = part56 + (size_t)b * kNcat;
    const float* p1 = part56 + (size_t)(64 + b) * kNcat;
    const float* q0 = pa2c + (size_t)b * (2 * kR);
    const float* q1 = pa2c + (size_t)(64 + b) * (2 * kR);
    const float* ib = i2h_pre + (size_t)(b * kT + t) * (5 * kR);

    const float S0 = p0[r]          + p1[r]          + ib[r]          + h2h_b[r];
    const float S1 = p0[kR + r]     + p1[kR + r]     + ib[kR + r]     + h2h_b[kR + r];
    const float S2 = p0[2 * kR + r] + p1[2 * kR + r] + ib[2 * kR + r] + h2h_b[2 * kR + r];
    const float S3 = p0[3 * kR + r] + p1[3 * kR + r] + q0[r]      + q1[r]      + ib[3 * kR + r] + h2h_b[3 * kR + r] + a2c_b[r];
    const float S4 = p0[4 * kR + r] + p1[4 * kR + r] + q0[kR + r] + q1[kR + r] + ib[4 * kR + r] + h2h_b[4 * kR + r] + a2c_b[kR + r];

    const float ing = fast_sig(S0);
    const float fg  = fast_sig(S1);
    const float og  = fast_sig(S2);
    const float gg  = fmaxf(S3, S4);
    const float nc  = fg * cbuf[idx] + ing * gg;
    const float nh  = og * fast_tanh(nc);
    cbuf[idx] = nc;
    h_all_bf[(size_t)(b * kT + t) * kR + r] = f2bf(nh);
}

// ---------------------------------------------------------------------------
// in-place log_softmax over V; one block per row. Online max/sum.
// ---------------------------------------------------------------------------
__global__ __launch_bounds__(256)
void log_softmax_kernel(float* __restrict__ out)
{
    __shared__ float mred[256];
    __shared__ float sred[256];
    const int tid = threadIdx.x;
    float* row = out + (size_t)blockIdx.x * kV;

    float m = -1e30f, s = 0.f;
    for (int v = tid; v < kV; v += 256) {
        const float x = row[v];
        if (x > m) { s = s * __expf(m - x) + 1.f; m = x; }
        else        s += __expf(x - m);
    }
    mred[tid] = m; sred[tid] = s; __syncthreads();
    for (int st = 128; st > 0; st >>= 1) {
        if (tid < st) {
            const float m2 = mred[tid + st], s2 = sred[tid + st];
            const float M = fmaxf(mred[tid], m2);
            sred[tid] = sred[tid] * __expf(mred[tid] - M) + s2 * __expf(m2 - M);
            mred[tid] = M;
        }
        __syncthreads();
    }
    const float ls = mred[0] + logf(sred[0]);
    for (int v = tid; v < kV; v += 256) row[v] -= ls;
}

extern "C" void kernel_launch(void* const* d_in, const int* in_sizes, int n_in,
                              void* d_out, int out_size, void* d_ws, size_t ws_size,
                              hipStream_t stream)
{
    const int*   seq       = (const int*)  d_in[0];
    const float* att_feats = (const float*)d_in[1];
    const float* embed_w   = (const float*)d_in[2];
    const float* ctx2att_w = (const float*)d_in[3];
    const float* ctx2att_b = (const float*)d_in[4];
    const float* h2att_w   = (const float*)d_in[5];
    const float* h2att_b   = (const float*)d_in[6];
    const float* alpha_w   = (const float*)d_in[7];
    const float* i2h_w     = (const float*)d_in[9];
    const float* i2h_b     = (const float*)d_in[10];
    const float* h2h_w     = (const float*)d_in[11];
    const float* h2h_b     = (const float*)d_in[12];
    const float* a2c_w     = (const float*)d_in[13];
    const float* a2c_b     = (const float*)d_in[14];
    const float* logit_w   = (const float*)d_in[15];
    const float* logit_b   = (const float*)d_in[16];
    float* out = (float*)d_out;

    float* ws = (float*)d_ws;
    size_t off = 0;
    auto alloc = [&](size_t nf) { float* p = ws + off; off += (nf + 3) & ~(size_t)3; return p; };

    unsigned short* af_bf      = (unsigned short*)alloc((size_t)kB * kL * kF / 2);   // 51 MB
    unsigned short* p_att_bf   = (unsigned short*)alloc((size_t)kB * kL * kH / 2);   // 12.8 MB
    unsigned short* ctx_hi     = (unsigned short*)alloc((size_t)kH * kF / 2);
    unsigned short* logit_hi   = (unsigned short*)alloc((size_t)kV * kR / 2);
    unsigned short* embed_bf   = (unsigned short*)alloc((size_t)kV * kEp / 2);
    unsigned short* i2h_bf     = (unsigned short*)alloc((size_t)5 * kR * kEp / 2);
    unsigned short* wcat_bf    = (unsigned short*)alloc((size_t)kNcat * kR / 2);     // 11.5 MB
    unsigned short* a2c_bf     = (unsigned short*)alloc((size_t)2 * kR * kF / 2);    // 8.4 MB
    unsigned short* h_all_bf   = (unsigned short*)alloc((size_t)kB * kT * kR / 2);
    unsigned short* h_zero_bf  = (unsigned short*)alloc((size_t)kB * kR / 2);
    unsigned short* att_res_bf = (unsigned short*)alloc((size_t)kB * kF / 2);
    float* i2h_pre = alloc((size_t)kB * kT * 5 * kR);    // 26 MB
    float* part56  = alloc((size_t)2 * kB * kNcat);      // 2.9 MB
    float* pa2c    = alloc((size_t)2 * kB * 2 * kR);     // 1 MB
    float* cbuf    = alloc((size_t)kB * kR);

    hipMemsetAsync(cbuf, 0, (size_t)kB * kR * sizeof(float), stream);
    hipMemsetAsync(h_zero_bf, 0, (size_t)kB * kR * sizeof(unsigned short), stream);
    hipMemsetAsync(embed_bf, 0, (size_t)kV * kEp * sizeof(unsigned short), stream);
    hipMemsetAsync(i2h_bf,   0, (size_t)5 * kR * kEp * sizeof(unsigned short), stream);

    // one-time conversions / packs
    conv_hi_kernel<<<2048, 256, 0, stream>>>(att_feats, af_bf, kB * kL * kF / 4);
    conv_hi_kernel<<<512, 256, 0, stream>>>(ctx2att_w, ctx_hi, kH * kF / 4);
    conv_hi_kernel<<<2048, 256, 0, stream>>>(logit_w, logit_hi, kV * kR / 4);
    conv_pad300_kernel<<<1024, 256, 0, stream>>>(embed_w, embed_bf, kV);
    conv_pad300_kernel<<<512, 256, 0, stream>>>(i2h_w, i2h_bf, 5 * kR);
    conv_hi_kernel<<<1024, 256, 0, stream>>>(h2h_w, wcat_bf, 5 * kR * kR / 4);
    conv_hi_kernel<<<256, 256, 0, stream>>>(h2att_w, wcat_bf + (size_t)5 * kR * kR, kH * kR / 4);
    conv_hi_kernel<<<1024, 256, 0, stream>>>(a2c_w, a2c_bf, 2 * kR * kF / 4);

    // p_att = att_feats @ ctx2att_w.T + b -> bf16   (12544 x 512, K=2048)
    gemm_bf_kernel<true, false><<<dim3(kH / 128, kB * kL / 128), 256, 0, stream>>>(
        af_bf, kF, ctx_hi, kF, ctx2att_b, p_att_bf, kH, kB * kL, kH, kF, nullptr);

    // i2h_pre = embed[seq] @ i2h_w.T + b   (1280 x 5120, K=320 padded)
    gemm_bf_kernel<false, true><<<dim3(5 * kR / 128, kB * kT / 128), 256, 0, stream>>>(
        embed_bf, kEp, i2h_bf, kEp, i2h_b, i2h_pre, 5 * kR, kB * kT, 5 * kR, kEp, seq);

    // 20-step recurrence: 4 launches per step
    for (int t = 0; t < kT; ++t) {
        const unsigned short* h_prev = (t == 0) ? h_zero_bf : (h_all_bf + (size_t)(t - 1) * kR);
        const int lda_h = (t == 0) ? kR : kT * kR;

        // part56 = h_prev @ [h2h | h2att].T   (64 x 5632, K=1024, ks=2)
        gemm_sums_kernel<<<dim3(kNcat / 64, 2), 256, 0, stream>>>(
            h_prev, lda_h, wcat_bf, kR, part56, kNcat, kR / 2);

        att_es_readout_kernel<<<dim3(4, kB), 256, 0, stream>>>(
            part56, h2att_b, p_att_bf, alpha_w, af_bf, att_res_bf);

        // pa2c = att_res @ a2c_w.T   (64 x 2048, K=2048, ks=2)
        gemm_sums_kernel<<<dim3(2 * kR / 64, 2), 256, 0, stream>>>(
            att_res_bf, kF, a2c_bf, kF, pa2c, 2 * kR, kF / 2);

        gates_kernel<<<dim3(kB * kR / 256), 256, 0, stream>>>(
            part56, pa2c, i2h_pre, h2h_b, a2c_b, cbuf, h_all_bf, t);
    }

    // logits = h_all @ logit_w.T + b -> out fp32  (1280 x 12001, K=1024)
    gemm_bf_kernel<false, false><<<dim3((kV + 127) / 128, kB * kT / 128), 256, 0, stream>>>(
        h_all_bf, kR, logit_hi, kR, logit_b, out, kV, kB * kT, kV, kR, nullptr);

    log_softmax_kernel<<<dim3(kB * kT), 256, 0, stream>>>(out);
}

// Round 13
// 2037.640 us; speedup vs baseline: 1.8603x; 1.0255x over previous
//
#include <hip/hip_runtime.h>
#include <math.h>

namespace {
constexpr int kV = 12001;
constexpr int kE = 300;
constexpr int kEp = 320;   // padded K for i2h
constexpr int kR = 1024;
constexpr int kH = 512;
constexpr int kF = 2048;
constexpr int kB = 64;
constexpr int kT = 20;
constexpr int kL = 196;
constexpr int kNcat = 5 * kR + kH;   // 5632: [h2h | h2att]
}

typedef __attribute__((ext_vector_type(8))) short short8;
typedef __attribute__((ext_vector_type(4))) float f32x4;

__device__ __forceinline__ unsigned short f2bf(float f) {
    unsigned u = __builtin_bit_cast(unsigned, f);
    u = (u + 0x7fffu + ((u >> 16) & 1u)) >> 16;
    return (unsigned short)u;
}
__device__ __forceinline__ float bf2f(unsigned short h) {
    unsigned u = ((unsigned)h) << 16;
    return __builtin_bit_cast(float, u);
}
__device__ __forceinline__ float fast_tanh(float x) {
    x = fminf(15.f, fmaxf(-15.f, x));
    const float e = __expf(2.f * x);
    return (e - 1.f) / (e + 1.f);
}
__device__ __forceinline__ float fast_sig(float x) {
    return 1.f / (1.f + __expf(-x));
}

// ---------------------------------------------------------------------------
// fp32 -> bf16 (n4 = count/4)
// ---------------------------------------------------------------------------
__global__ __launch_bounds__(256)
void conv_hi_kernel(const float* __restrict__ in, unsigned short* __restrict__ out, int n4)
{
    for (int i = blockIdx.x * 256 + threadIdx.x; i < n4; i += gridDim.x * 256) {
        const float4 v = ((const float4*)in)[i];
        ushort4 o;
        o.x = f2bf(v.x); o.y = f2bf(v.y); o.z = f2bf(v.z); o.w = f2bf(v.w);
        ((ushort4*)out)[i] = o;
    }
}

// fp32 rows of 300 -> bf16 rows padded to 320 (pads pre-zeroed by memset)
__global__ __launch_bounds__(256)
void conv_pad300_kernel(const float* __restrict__ in, unsigned short* __restrict__ out, int rows)
{
    const int total = rows * 75;
    for (int i = blockIdx.x * 256 + threadIdx.x; i < total; i += gridDim.x * 256) {
        const int r = i / 75, c = i - r * 75;
        const float4 v = *(const float4*)(in + (size_t)r * kE + c * 4);
        ushort4 o;
        o.x = f2bf(v.x); o.y = f2bf(v.y); o.z = f2bf(v.z); o.w = f2bf(v.w);
        *(ushort4*)(out + (size_t)r * kEp + c * 4) = o;
    }
}

// ---------------------------------------------------------------------------
// Pure-bf16 MFMA GEMM (128x128 tile): C = A[row(m)] @ W.T + bias
// ---------------------------------------------------------------------------
template<bool OUT_BF16, bool GATHER>
__global__ __launch_bounds__(256)
void gemm_bf_kernel(const unsigned short* __restrict__ Ah, int lda,
                    const unsigned short* __restrict__ Wh, int ldw,
                    const float* __restrict__ bias,
                    void* __restrict__ Cp, int ldc,
                    int M, int N, int K,
                    const int* __restrict__ ridx)
{
    __shared__ unsigned short sA[128][40];
    __shared__ unsigned short sW[128][40];
    const int tid = threadIdx.x;
    const int m0 = blockIdx.y * 128;
    const int n0 = blockIdx.x * 128;
    const int wave = tid >> 6, lane = tid & 63;
    const int wm = wave >> 1, wn = wave & 1;
    const int lrow = lane & 15, lkg = lane >> 4;

    f32x4 acc[4][4];
    #pragma unroll
    for (int mi = 0; mi < 4; ++mi)
        #pragma unroll
        for (int ni = 0; ni < 4; ++ni)
            acc[mi][ni] = (f32x4){0.f, 0.f, 0.f, 0.f};

    for (int k0 = 0; k0 < K; k0 += 32) {
        for (int g = tid; g < 512; g += 256) {
            const int r = g >> 2, q = g & 3;
            const int k = k0 + q * 8;
            const int m = m0 + r;
            const int row = GATHER ? ridx[m] : m;
            *(short8*)&sA[r][q * 8] = *(const short8*)(Ah + (size_t)row * lda + k);
        }
        for (int g = tid; g < 512; g += 256) {
            const int r = g >> 2, q = g & 3;
            const int k = k0 + q * 8;
            const int n = n0 + r;
            short8 v = (short8){0,0,0,0,0,0,0,0};
            if (n < N) v = *(const short8*)(Wh + (size_t)n * ldw + k);
            *(short8*)&sW[r][q * 8] = v;
        }
        __syncthreads();

        short8 af[4], wf[4];
        #pragma unroll
        for (int mi = 0; mi < 4; ++mi)
            af[mi] = *(const short8*)&sA[wm * 64 + mi * 16 + lrow][lkg * 8];
        #pragma unroll
        for (int ni = 0; ni < 4; ++ni)
            wf[ni] = *(const short8*)&sW[wn * 64 + ni * 16 + lrow][lkg * 8];
        #pragma unroll
        for (int mi = 0; mi < 4; ++mi)
            #pragma unroll
            for (int ni = 0; ni < 4; ++ni)
                acc[mi][ni] = __builtin_amdgcn_mfma_f32_16x16x32_bf16(af[mi], wf[ni], acc[mi][ni], 0, 0, 0);
        __syncthreads();
    }

    #pragma unroll
    for (int mi = 0; mi < 4; ++mi) {
        const int mbase = m0 + wm * 64 + mi * 16 + lkg * 4;
        #pragma unroll
        for (int ni = 0; ni < 4; ++ni) {
            const int n = n0 + wn * 64 + ni * 16 + lrow;
            if (n >= N) continue;
            const float bb = bias ? bias[n] : 0.f;
            #pragma unroll
            for (int r = 0; r < 4; ++r) {
                const int m = mbase + r;
                const float v = acc[mi][ni][r] + bb;
                if (OUT_BF16) ((unsigned short*)Cp)[(size_t)m * ldc + n] = f2bf(v);
                else          ((float*)Cp)[(size_t)m * ldc + n] = v;
            }
        }
    }
}

// ---------------------------------------------------------------------------
// Small-M sums GEMM: part[ks][64][N] = A(64 x Ktot) @ W(N x Ktot).T  (K-split)
// BM=64, BN=64, BK=32. grid (N/64, ksplit). Kblk = Ktot/ksplit.
// ---------------------------------------------------------------------------
__global__ __launch_bounds__(256)
void gemm_sums_kernel(const unsigned short* __restrict__ A, int lda,
                      const unsigned short* __restrict__ W, int ldw,
                      float* __restrict__ part, int N, int Kblk)
{
    __shared__ unsigned short sA[64][40];
    __shared__ unsigned short sW[64][40];
    const int tid = threadIdx.x;
    const int n0 = blockIdx.x * 64;
    const int ks = blockIdx.y;
    const int kbeg = ks * Kblk;
    const int wave = tid >> 6, lane = tid & 63;
    const int lrow = lane & 15, lkg = lane >> 4;

    f32x4 acc[4];
    #pragma unroll
    for (int mi = 0; mi < 4; ++mi) acc[mi] = (f32x4){0.f, 0.f, 0.f, 0.f};

    const int r = tid >> 2, q = tid & 3;
    for (int k0 = kbeg; k0 < kbeg + Kblk; k0 += 32) {
        *(short8*)&sA[r][q * 8] = *(const short8*)(A + (size_t)r * lda + k0 + q * 8);
        *(short8*)&sW[r][q * 8] = *(const short8*)(W + (size_t)(n0 + r) * ldw + k0 + q * 8);
        __syncthreads();
        const short8 wf = *(const short8*)&sW[wave * 16 + lrow][lkg * 8];
        #pragma unroll
        for (int mi = 0; mi < 4; ++mi) {
            const short8 af = *(const short8*)&sA[mi * 16 + lrow][lkg * 8];
            acc[mi] = __builtin_amdgcn_mfma_f32_16x16x32_bf16(af, wf, acc[mi], 0, 0, 0);
        }
        __syncthreads();
    }

    float* po = part + (size_t)ks * 64 * N;
    const int n = n0 + wave * 16 + lrow;
    #pragma unroll
    for (int mi = 0; mi < 4; ++mi)
        #pragma unroll
        for (int rr = 0; rr < 4; ++rr)
            po[(size_t)(mi * 16 + lkg * 4 + rr) * N + n] = acc[mi][rr];
}

// ---------------------------------------------------------------------------
// Step kernel: e + softmax (4x redundant per fc) + paired readout of
// pre_a2c cols (r, 1024+r) + full gates -> cbuf, h_all_bf[t].
// grid (4 fc, 64 b), 256 thr; thread owns r = fc*256 + tid.
// ---------------------------------------------------------------------------
__global__ __launch_bounds__(256)
void att_step_kernel(const float* __restrict__ part56,
                     const float* __restrict__ h2att_b,
                     const unsigned short* __restrict__ p_att_bf,
                     const float* __restrict__ alpha_w,
                     const unsigned short* __restrict__ pre_bf,
                     const unsigned short* __restrict__ i2h_pre_bf,
                     const float* __restrict__ h2h_b,
                     float* __restrict__ cbuf,
                     unsigned short* __restrict__ h_all_bf,
                     int t)
{
    const int fc = blockIdx.x, b = blockIdx.y;
    const int tid = threadIdx.x;
    const int wave = tid >> 6, lane = tid & 63;
    __shared__ float ahT[8][64];
    __shared__ float awT[8][64];
    __shared__ float esm[kL];
    __shared__ float wsm[kL];
    __shared__ float red2[2];

    for (int i = tid; i < kH; i += 256) {
        const size_t base = (size_t)b * kNcat + 5 * kR + i;
        ahT[i & 7][i >> 3] = part56[base] + part56[(size_t)64 * kNcat + base] + h2att_b[i];
        awT[i & 7][i >> 3] = alpha_w[i];
    }
    __syncthreads();

    // e: 4 waves, wave handles l = wave, wave+4, ...
    for (int l = wave; l < kL; l += 4) {
        const short8 pv = *(const short8*)(p_att_bf + ((size_t)b * kL + l) * kH + lane * 8);
        float a = 0.f;
        #pragma unroll
        for (int j = 0; j < 8; ++j)
            a += fast_tanh(bf2f(((const unsigned short*)&pv)[j]) + ahT[j][lane]) * awT[j][lane];
        #pragma unroll
        for (int off = 32; off; off >>= 1) a += __shfl_xor(a, off, 64);
        if (lane == 0) esm[l] = a;
    }
    __syncthreads();

    if (wave == 0) {
        float m = -1e30f;
        for (int l = lane; l < kL; l += 64) m = fmaxf(m, esm[l]);
        #pragma unroll
        for (int off = 32; off; off >>= 1) m = fmaxf(m, __shfl_xor(m, off, 64));
        float ssum = 0.f;
        for (int l = lane; l < kL; l += 64) ssum += __expf(esm[l] - m);
        #pragma unroll
        for (int off = 32; off; off >>= 1) ssum += __shfl_xor(ssum, off, 64);
        if (lane == 0) { red2[0] = m; red2[1] = 1.f / ssum; }
    }
    __syncthreads();
    if (tid < kL) wsm[tid] = __expf(esm[tid] - red2[0]) * red2[1];
    __syncthreads();

    // paired readout: itr cols r and 1024+r  (pre_a2c includes a2c_b; sum_l w = 1)
    const int r = fc * 256 + tid;
    float s3 = 0.f, s4 = 0.f;
    const unsigned short* base = pre_bf + (size_t)b * kL * kF + r;
    #pragma unroll 8
    for (int l = 0; l < kL; ++l) {
        const float wl = wsm[l];
        s3 += wl * bf2f(base[(size_t)l * kF]);
        s4 += wl * bf2f(base[(size_t)l * kF + kR]);
    }

    // gates
    const float* p0 = part56 + (size_t)b * kNcat;
    const float* p1 = part56 + (size_t)(64 + b) * kNcat;
    const unsigned short* ib = i2h_pre_bf + (size_t)(b * kT + t) * (5 * kR);

    const float S0 = p0[r]          + p1[r]          + bf2f(ib[r])          + h2h_b[r];
    const float S1 = p0[kR + r]     + p1[kR + r]     + bf2f(ib[kR + r])     + h2h_b[kR + r];
    const float S2 = p0[2 * kR + r] + p1[2 * kR + r] + bf2f(ib[2 * kR + r]) + h2h_b[2 * kR + r];
    const float S3 = p0[3 * kR + r] + p1[3 * kR + r] + s3 + bf2f(ib[3 * kR + r]) + h2h_b[3 * kR + r];
    const float S4 = p0[4 * kR + r] + p1[4 * kR + r] + s4 + bf2f(ib[4 * kR + r]) + h2h_b[4 * kR + r];

    const float ing = fast_sig(S0);
    const float fg  = fast_sig(S1);
    const float og  = fast_sig(S2);
    const float gg  = fmaxf(S3, S4);
    const int idx = b * kR + r;
    const float nc = fg * cbuf[idx] + ing * gg;
    const float nh = og * fast_tanh(nc);
    cbuf[idx] = nc;
    h_all_bf[(size_t)(b * kT + t) * kR + r] = f2bf(nh);
}

// ---------------------------------------------------------------------------
// in-place log_softmax over V; one block per row. Online max/sum.
// ---------------------------------------------------------------------------
__global__ __launch_bounds__(256)
void log_softmax_kernel(float* __restrict__ out)
{
    __shared__ float mred[256];
    __shared__ float sred[256];
    const int tid = threadIdx.x;
    float* row = out + (size_t)blockIdx.x * kV;

    float m = -1e30f, s = 0.f;
    for (int v = tid; v < kV; v += 256) {
        const float x = row[v];
        if (x > m) { s = s * __expf(m - x) + 1.f; m = x; }
        else        s += __expf(x - m);
    }
    mred[tid] = m; sred[tid] = s; __syncthreads();
    for (int st = 128; st > 0; st >>= 1) {
        if (tid < st) {
            const float m2 = mred[tid + st], s2 = sred[tid + st];
            const float M = fmaxf(mred[tid], m2);
            sred[tid] = sred[tid] * __expf(mred[tid] - M) + s2 * __expf(m2 - M);
            mred[tid] = M;
        }
        __syncthreads();
    }
    const float ls = mred[0] + logf(sred[0]);
    for (int v = tid; v < kV; v += 256) row[v] -= ls;
}

extern "C" void kernel_launch(void* const* d_in, const int* in_sizes, int n_in,
                              void* d_out, int out_size, void* d_ws, size_t ws_size,
                              hipStream_t stream)
{
    const int*   seq       = (const int*)  d_in[0];
    const float* att_feats = (const float*)d_in[1];
    const float* embed_w   = (const float*)d_in[2];
    const float* ctx2att_w = (const float*)d_in[3];
    const float* ctx2att_b = (const float*)d_in[4];
    const float* h2att_w   = (const float*)d_in[5];
    const float* h2att_b   = (const float*)d_in[6];
    const float* alpha_w   = (const float*)d_in[7];
    const float* i2h_w     = (const float*)d_in[9];
    const float* i2h_b     = (const float*)d_in[10];
    const float* h2h_w     = (const float*)d_in[11];
    const float* h2h_b     = (const float*)d_in[12];
    const float* a2c_w     = (const float*)d_in[13];
    const float* a2c_b     = (const float*)d_in[14];
    const float* logit_w   = (const float*)d_in[15];
    const float* logit_b   = (const float*)d_in[16];
    float* out = (float*)d_out;

    float* ws = (float*)d_ws;
    size_t off = 0;
    auto alloc = [&](size_t nf) { float* p = ws + off; off += (nf + 3) & ~(size_t)3; return p; };

    unsigned short* af_bf      = (unsigned short*)alloc((size_t)kB * kL * kF / 2);   // 51 MB
    unsigned short* pre_bf     = (unsigned short*)alloc((size_t)kB * kL * kF / 2);   // 51 MB
    unsigned short* p_att_bf   = (unsigned short*)alloc((size_t)kB * kL * kH / 2);   // 12.8 MB
    unsigned short* ctx_hi     = (unsigned short*)alloc((size_t)kH * kF / 2);
    unsigned short* logit_hi   = (unsigned short*)alloc((size_t)kV * kR / 2);
    unsigned short* embed_bf   = (unsigned short*)alloc((size_t)kV * kEp / 2);
    unsigned short* i2h_bf     = (unsigned short*)alloc((size_t)5 * kR * kEp / 2);
    unsigned short* wcat_bf    = (unsigned short*)alloc((size_t)kNcat * kR / 2);     // 11.5 MB
    unsigned short* a2c_bf     = (unsigned short*)alloc((size_t)2 * kR * kF / 2);    // 8.4 MB
    unsigned short* h_all_bf   = (unsigned short*)alloc((size_t)kB * kT * kR / 2);
    unsigned short* h_zero_bf  = (unsigned short*)alloc((size_t)kB * kR / 2);
    unsigned short* i2h_pre_bf = (unsigned short*)alloc((size_t)kB * kT * 5 * kR / 2); // 13 MB
    float* part56  = alloc((size_t)2 * kB * kNcat);      // 2.9 MB
    float* cbuf    = alloc((size_t)kB * kR);

    hipMemsetAsync(cbuf, 0, (size_t)kB * kR * sizeof(float), stream);
    hipMemsetAsync(h_zero_bf, 0, (size_t)kB * kR * sizeof(unsigned short), stream);
    hipMemsetAsync(embed_bf, 0, (size_t)kV * kEp * sizeof(unsigned short), stream);
    hipMemsetAsync(i2h_bf,   0, (size_t)5 * kR * kEp * sizeof(unsigned short), stream);

    // one-time conversions / packs
    conv_hi_kernel<<<2048, 256, 0, stream>>>(att_feats, af_bf, kB * kL * kF / 4);
    conv_hi_kernel<<<512, 256, 0, stream>>>(ctx2att_w, ctx_hi, kH * kF / 4);
    conv_hi_kernel<<<2048, 256, 0, stream>>>(logit_w, logit_hi, kV * kR / 4);
    conv_pad300_kernel<<<1024, 256, 0, stream>>>(embed_w, embed_bf, kV);
    conv_pad300_kernel<<<512, 256, 0, stream>>>(i2h_w, i2h_bf, 5 * kR);
    conv_hi_kernel<<<1024, 256, 0, stream>>>(h2h_w, wcat_bf, 5 * kR * kR / 4);
    conv_hi_kernel<<<256, 256, 0, stream>>>(h2att_w, wcat_bf + (size_t)5 * kR * kR, kH * kR / 4);
    conv_hi_kernel<<<1024, 256, 0, stream>>>(a2c_w, a2c_bf, 2 * kR * kF / 4);

    // p_att = att_feats @ ctx2att_w.T + b -> bf16   (12544 x 512, K=2048)
    gemm_bf_kernel<true, false><<<dim3(kH / 128, kB * kL / 128), 256, 0, stream>>>(
        af_bf, kF, ctx_hi, kF, ctx2att_b, p_att_bf, kH, kB * kL, kH, kF, nullptr);

    // i2h_pre = embed[seq] @ i2h_w.T + b -> bf16   (1280 x 5120, K=320 padded)
    gemm_bf_kernel<true, true><<<dim3(5 * kR / 128, kB * kT / 128), 256, 0, stream>>>(
        embed_bf, kEp, i2h_bf, kEp, i2h_b, i2h_pre_bf, 5 * kR, kB * kT, 5 * kR, kEp, seq);

    // pre_a2c = att_feats @ a2c_w.T + a2c_b -> bf16  (12544 x 2048, K=2048)
    gemm_bf_kernel<true, false><<<dim3(kF / 128, kB * kL / 128), 256, 0, stream>>>(
        af_bf, kF, a2c_bf, kF, a2c_b, pre_bf, kF, kB * kL, kF, kF, nullptr);

    // 20-step recurrence: 2 launches per step
    for (int t = 0; t < kT; ++t) {
        const unsigned short* h_prev = (t == 0) ? h_zero_bf : (h_all_bf + (size_t)(t - 1) * kR);
        const int lda_h = (t == 0) ? kR : kT * kR;

        // part56 = h_prev @ [h2h | h2att].T   (64 x 5632, K=1024, ks=2)
        gemm_sums_kernel<<<dim3(kNcat / 64, 2), 256, 0, stream>>>(
            h_prev, lda_h, wcat_bf, kR, part56, kNcat, kR / 2);

        att_step_kernel<<<dim3(4, kB), 256, 0, stream>>>(
            part56, h2att_b, p_att_bf, alpha_w, pre_bf, i2h_pre_bf, h2h_b,
            cbuf, h_all_bf, t);
    }

    // logits = h_all @ logit_w.T + b -> out fp32  (1280 x 12001, K=1024)
    gemm_bf_kernel<false, false><<<dim3((kV + 127) / 128, kB * kT / 128), 256, 0, stream>>>(
        h_all_bf, kR, logit_hi, kR, logit_b, out, kV, kB * kT, kV, kR, nullptr);

    log_softmax_kernel<<<dim3(kB * kT), 256, 0, stream>>>(out);
}

// Round 14
// 1848.223 us; speedup vs baseline: 2.0510x; 1.1025x over previous
//
#include <hip/hip_runtime.h>
#include <math.h>

namespace {
constexpr int kV = 12001;
constexpr int kE = 300;
constexpr int kEp = 320;   // padded K for i2h
constexpr int kR = 1024;
constexpr int kH = 512;
constexpr int kF = 2048;
constexpr int kB = 64;
constexpr int kT = 20;
constexpr int kL = 196;
constexpr int kNcat = 5 * kR + kH;   // 5632: [h2h | h2att]
}

typedef __attribute__((ext_vector_type(8))) short short8;
typedef __attribute__((ext_vector_type(4))) float f32x4;

#define GLB_PTR(p) ((const __attribute__((address_space(1))) void*)(p))
#define LDS_PTR(p) ((__attribute__((address_space(3))) void*)(p))

__device__ __forceinline__ unsigned short f2bf(float f) {
    unsigned u = __builtin_bit_cast(unsigned, f);
    u = (u + 0x7fffu + ((u >> 16) & 1u)) >> 16;
    return (unsigned short)u;
}
__device__ __forceinline__ float bf2f(unsigned short h) {
    unsigned u = ((unsigned)h) << 16;
    return __builtin_bit_cast(float, u);
}
__device__ __forceinline__ float fast_tanh(float x) {
    x = fminf(15.f, fmaxf(-15.f, x));
    const float e = __expf(2.f * x);
    return (e - 1.f) / (e + 1.f);
}
__device__ __forceinline__ float fast_sig(float x) {
    return 1.f / (1.f + __expf(-x));
}

// ---------------------------------------------------------------------------
// fp32 -> bf16 (n4 = count/4)
// ---------------------------------------------------------------------------
__global__ __launch_bounds__(256)
void conv_hi_kernel(const float* __restrict__ in, unsigned short* __restrict__ out, int n4)
{
    for (int i = blockIdx.x * 256 + threadIdx.x; i < n4; i += gridDim.x * 256) {
        const float4 v = ((const float4*)in)[i];
        ushort4 o;
        o.x = f2bf(v.x); o.y = f2bf(v.y); o.z = f2bf(v.z); o.w = f2bf(v.w);
        ((ushort4*)out)[i] = o;
    }
}

// fp32 rows of 300 -> bf16 rows padded to 320 (pads pre-zeroed by memset)
__global__ __launch_bounds__(256)
void conv_pad300_kernel(const float* __restrict__ in, unsigned short* __restrict__ out, int rows)
{
    const int total = rows * 75;
    for (int i = blockIdx.x * 256 + threadIdx.x; i < total; i += gridDim.x * 256) {
        const int r = i / 75, c = i - r * 75;
        const float4 v = *(const float4*)(in + (size_t)r * kE + c * 4);
        ushort4 o;
        o.x = f2bf(v.x); o.y = f2bf(v.y); o.z = f2bf(v.z); o.w = f2bf(v.w);
        *(ushort4*)(out + (size_t)r * kEp + c * 4) = o;
    }
}

// ---------------------------------------------------------------------------
// Pure-bf16 MFMA GEMM with width-16 global_load_lds staging (m97 structure).
// 128x128 tile, BK=32, 4 waves, LINEAR LDS [128][32] (lane map row=l>>2,
// chunk=l&3 makes HW's base+lane*16 exactly row-major). C = A[row(m)]@W.T + b
// M % 128 == 0, K % 32 == 0; N edge: OOB W rows read adjacent ws (harmless,
// those acc columns are never written).
// ---------------------------------------------------------------------------
template<bool OUT_BF16, bool GATHER>
__global__ __launch_bounds__(256)
void gemm_glds_kernel(const unsigned short* __restrict__ Ah, int lda,
                      const unsigned short* __restrict__ Wh, int ldw,
                      const float* __restrict__ bias,
                      void* __restrict__ Cp, int ldc,
                      int M, int N, int K,
                      const int* __restrict__ ridx)
{
    __shared__ __align__(16) unsigned short sA[128 * 32];
    __shared__ __align__(16) unsigned short sW[128 * 32];
    const int tid = threadIdx.x;
    const int m0 = blockIdx.y * 128;
    const int n0 = blockIdx.x * 128;
    const int wave = tid >> 6, lane = tid & 63;
    const int wm = wave >> 1, wn = wave & 1;
    const int lrow = lane & 15, lkg = lane >> 4;

    const int rsub   = lane >> 2;        // 0..15 row within 16-row issue
    const int cchunk = (lane & 3) * 8;   // element offset of 8-elem chunk

    f32x4 acc[4][4];
    #pragma unroll
    for (int mi = 0; mi < 4; ++mi)
        #pragma unroll
        for (int ni = 0; ni < 4; ++ni)
            acc[mi][ni] = (f32x4){0.f, 0.f, 0.f, 0.f};

    for (int k0 = 0; k0 < K; k0 += 32) {
        // A tile: wave stages rows [wave*32, wave*32+32) via 2 issues x 16 rows
        #pragma unroll
        for (int j = 0; j < 2; ++j) {
            const int mrow = m0 + wave * 32 + j * 16 + rsub;
            const int row = GATHER ? ridx[mrow] : mrow;
            __builtin_amdgcn_global_load_lds(
                GLB_PTR(Ah + (size_t)row * lda + k0 + cchunk),
                LDS_PTR(sA + wave * 1024 + j * 512), 16, 0, 0);
        }
        // W tile: wave stages rows [wave*32, wave*32+32)
        #pragma unroll
        for (int j = 0; j < 2; ++j) {
            const int n = n0 + wave * 32 + j * 16 + rsub;
            __builtin_amdgcn_global_load_lds(
                GLB_PTR(Wh + (size_t)n * ldw + k0 + cchunk),
                LDS_PTR(sW + wave * 1024 + j * 512), 16, 0, 0);
        }
        __syncthreads();

        short8 af[4], wf[4];
        #pragma unroll
        for (int mi = 0; mi < 4; ++mi)
            af[mi] = *(const short8*)(sA + (wm * 64 + mi * 16 + lrow) * 32 + lkg * 8);
        #pragma unroll
        for (int ni = 0; ni < 4; ++ni)
            wf[ni] = *(const short8*)(sW + (wn * 64 + ni * 16 + lrow) * 32 + lkg * 8);
        #pragma unroll
        for (int mi = 0; mi < 4; ++mi)
            #pragma unroll
            for (int ni = 0; ni < 4; ++ni)
                acc[mi][ni] = __builtin_amdgcn_mfma_f32_16x16x32_bf16(af[mi], wf[ni], acc[mi][ni], 0, 0, 0);
        __syncthreads();
    }

    // epilogue: row = (lane>>4)*4 + reg, col = lane&15 (m89-verified layout)
    #pragma unroll
    for (int mi = 0; mi < 4; ++mi) {
        const int mbase = m0 + wm * 64 + mi * 16 + lkg * 4;
        #pragma unroll
        for (int ni = 0; ni < 4; ++ni) {
            const int n = n0 + wn * 64 + ni * 16 + lrow;
            if (n >= N) continue;
            const float bb = bias ? bias[n] : 0.f;
            #pragma unroll
            for (int r = 0; r < 4; ++r) {
                const int m = mbase + r;
                const float v = acc[mi][ni][r] + bb;
                if (OUT_BF16) ((unsigned short*)Cp)[(size_t)m * ldc + n] = f2bf(v);
                else          ((float*)Cp)[(size_t)m * ldc + n] = v;
            }
        }
    }
}

// ---------------------------------------------------------------------------
// Small-M sums GEMM: part[ks][64][N] = A(64 x Ktot) @ W(N x Ktot).T  (K-split)
// BM=64, BN=64, BK=32. grid (N/64, ksplit). Kblk = Ktot/ksplit.
// ---------------------------------------------------------------------------
__global__ __launch_bounds__(256)
void gemm_sums_kernel(const unsigned short* __restrict__ A, int lda,
                      const unsigned short* __restrict__ W, int ldw,
                      float* __restrict__ part, int N, int Kblk)
{
    __shared__ unsigned short sA[64][40];
    __shared__ unsigned short sW[64][40];
    const int tid = threadIdx.x;
    const int n0 = blockIdx.x * 64;
    const int ks = blockIdx.y;
    const int kbeg = ks * Kblk;
    const int wave = tid >> 6, lane = tid & 63;
    const int lrow = lane & 15, lkg = lane >> 4;

    f32x4 acc[4];
    #pragma unroll
    for (int mi = 0; mi < 4; ++mi) acc[mi] = (f32x4){0.f, 0.f, 0.f, 0.f};

    const int r = tid >> 2, q = tid & 3;
    for (int k0 = kbeg; k0 < kbeg + Kblk; k0 += 32) {
        *(short8*)&sA[r][q * 8] = *(const short8*)(A + (size_t)r * lda + k0 + q * 8);
        *(short8*)&sW[r][q * 8] = *(const short8*)(W + (size_t)(n0 + r) * ldw + k0 + q * 8);
        __syncthreads();
        const short8 wf = *(const short8*)&sW[wave * 16 + lrow][lkg * 8];
        #pragma unroll
        for (int mi = 0; mi < 4; ++mi) {
            const short8 af = *(const short8*)&sA[mi * 16 + lrow][lkg * 8];
            acc[mi] = __builtin_amdgcn_mfma_f32_16x16x32_bf16(af, wf, acc[mi], 0, 0, 0);
        }
        __syncthreads();
    }

    float* po = part + (size_t)ks * 64 * N;
    const int n = n0 + wave * 16 + lrow;
    #pragma unroll
    for (int mi = 0; mi < 4; ++mi)
        #pragma unroll
        for (int rr = 0; rr < 4; ++rr)
            po[(size_t)(mi * 16 + lkg * 4 + rr) * N + n] = acc[mi][rr];
}

// ---------------------------------------------------------------------------
// Step kernel: e + softmax (4x redundant per fc) + paired readout of
// pre_a2c cols (r, 1024+r) + full gates -> cbuf, h_all_bf[t].
// grid (4 fc, 64 b), 256 thr; thread owns r = fc*256 + tid.
// ---------------------------------------------------------------------------
__global__ __launch_bounds__(256)
void att_step_kernel(const float* __restrict__ part56,
                     const float* __restrict__ h2att_b,
                     const unsigned short* __restrict__ p_att_bf,
                     const float* __restrict__ alpha_w,
                     const unsigned short* __restrict__ pre_bf,
                     const unsigned short* __restrict__ i2h_pre_bf,
                     const float* __restrict__ h2h_b,
                     float* __restrict__ cbuf,
                     unsigned short* __restrict__ h_all_bf,
                     int t)
{
    const int fc = blockIdx.x, b = blockIdx.y;
    const int tid = threadIdx.x;
    const int wave = tid >> 6, lane = tid & 63;
    __shared__ float ahT[8][64];
    __shared__ float awT[8][64];
    __shared__ float esm[kL];
    __shared__ float wsm[kL];
    __shared__ float red2[2];

    for (int i = tid; i < kH; i += 256) {
        const size_t base = (size_t)b * kNcat + 5 * kR + i;
        ahT[i & 7][i >> 3] = part56[base] + part56[(size_t)64 * kNcat + base] + h2att_b[i];
        awT[i & 7][i >> 3] = alpha_w[i];
    }
    __syncthreads();

    // e: 4 waves, wave handles l = wave, wave+4, ...
    for (int l = wave; l < kL; l += 4) {
        const short8 pv = *(const short8*)(p_att_bf + ((size_t)b * kL + l) * kH + lane * 8);
        float a = 0.f;
        #pragma unroll
        for (int j = 0; j < 8; ++j)
            a += fast_tanh(bf2f(((const unsigned short*)&pv)[j]) + ahT[j][lane]) * awT[j][lane];
        #pragma unroll
        for (int off = 32; off; off >>= 1) a += __shfl_xor(a, off, 64);
        if (lane == 0) esm[l] = a;
    }
    __syncthreads();

    if (wave == 0) {
        float m = -1e30f;
        for (int l = lane; l < kL; l += 64) m = fmaxf(m, esm[l]);
        #pragma unroll
        for (int off = 32; off; off >>= 1) m = fmaxf(m, __shfl_xor(m, off, 64));
        float ssum = 0.f;
        for (int l = lane; l < kL; l += 64) ssum += __expf(esm[l] - m);
        #pragma unroll
        for (int off = 32; off; off >>= 1) ssum += __shfl_xor(ssum, off, 64);
        if (lane == 0) { red2[0] = m; red2[1] = 1.f / ssum; }
    }
    __syncthreads();
    if (tid < kL) wsm[tid] = __expf(esm[tid] - red2[0]) * red2[1];
    __syncthreads();

    // paired readout: itr cols r and 1024+r  (pre_a2c includes a2c_b; sum_l w = 1)
    const int r = fc * 256 + tid;
    float s3 = 0.f, s4 = 0.f;
    const unsigned short* base = pre_bf + (size_t)b * kL * kF + r;
    #pragma unroll 8
    for (int l = 0; l < kL; ++l) {
        const float wl = wsm[l];
        s3 += wl * bf2f(base[(size_t)l * kF]);
        s4 += wl * bf2f(base[(size_t)l * kF + kR]);
    }

    // gates
    const float* p0 = part56 + (size_t)b * kNcat;
    const float* p1 = part56 + (size_t)(64 + b) * kNcat;
    const unsigned short* ib = i2h_pre_bf + (size_t)(b * kT + t) * (5 * kR);

    const float S0 = p0[r]          + p1[r]          + bf2f(ib[r])          + h2h_b[r];
    const float S1 = p0[kR + r]     + p1[kR + r]     + bf2f(ib[kR + r])     + h2h_b[kR + r];
    const float S2 = p0[2 * kR + r] + p1[2 * kR + r] + bf2f(ib[2 * kR + r]) + h2h_b[2 * kR + r];
    const float S3 = p0[3 * kR + r] + p1[3 * kR + r] + s3 + bf2f(ib[3 * kR + r]) + h2h_b[3 * kR + r];
    const float S4 = p0[4 * kR + r] + p1[4 * kR + r] + s4 + bf2f(ib[4 * kR + r]) + h2h_b[4 * kR + r];

    const float ing = fast_sig(S0);
    const float fg  = fast_sig(S1);
    const float og  = fast_sig(S2);
    const float gg  = fmaxf(S3, S4);
    const int idx = b * kR + r;
    const float nc = fg * cbuf[idx] + ing * gg;
    const float nh = og * fast_tanh(nc);
    cbuf[idx] = nc;
    h_all_bf[(size_t)(b * kT + t) * kR + r] = f2bf(nh);
}

// ---------------------------------------------------------------------------
// in-place log_softmax over V; one block per row. Online max/sum.
// ---------------------------------------------------------------------------
__global__ __launch_bounds__(256)
void log_softmax_kernel(float* __restrict__ out)
{
    __shared__ float mred[256];
    __shared__ float sred[256];
    const int tid = threadIdx.x;
    float* row = out + (size_t)blockIdx.x * kV;

    float m = -1e30f, s = 0.f;
    for (int v = tid; v < kV; v += 256) {
        const float x = row[v];
        if (x > m) { s = s * __expf(m - x) + 1.f; m = x; }
        else        s += __expf(x - m);
    }
    mred[tid] = m; sred[tid] = s; __syncthreads();
    for (int st = 128; st > 0; st >>= 1) {
        if (tid < st) {
            const float m2 = mred[tid + st], s2 = sred[tid + st];
            const float M = fmaxf(mred[tid], m2);
            sred[tid] = sred[tid] * __expf(mred[tid] - M) + s2 * __expf(m2 - M);
            mred[tid] = M;
        }
        __syncthreads();
    }
    const float ls = mred[0] + logf(sred[0]);
    for (int v = tid; v < kV; v += 256) row[v] -= ls;
}

extern "C" void kernel_launch(void* const* d_in, const int* in_sizes, int n_in,
                              void* d_out, int out_size, void* d_ws, size_t ws_size,
                              hipStream_t stream)
{
    const int*   seq       = (const int*)  d_in[0];
    const float* att_feats = (const float*)d_in[1];
    const float* embed_w   = (const float*)d_in[2];
    const float* ctx2att_w = (const float*)d_in[3];
    const float* ctx2att_b = (const float*)d_in[4];
    const float* h2att_w   = (const float*)d_in[5];
    const float* h2att_b   = (const float*)d_in[6];
    const float* alpha_w   = (const float*)d_in[7];
    const float* i2h_w     = (const float*)d_in[9];
    const float* i2h_b     = (const float*)d_in[10];
    const float* h2h_w     = (const float*)d_in[11];
    const float* h2h_b     = (const float*)d_in[12];
    const float* a2c_w     = (const float*)d_in[13];
    const float* a2c_b     = (const float*)d_in[14];
    const float* logit_w   = (const float*)d_in[15];
    const float* logit_b   = (const float*)d_in[16];
    float* out = (float*)d_out;

    float* ws = (float*)d_ws;
    size_t off = 0;
    auto alloc = [&](size_t nf) { float* p = ws + off; off += (nf + 3) & ~(size_t)3; return p; };

    unsigned short* af_bf      = (unsigned short*)alloc((size_t)kB * kL * kF / 2);   // 51 MB
    unsigned short* pre_bf     = (unsigned short*)alloc((size_t)kB * kL * kF / 2);   // 51 MB
    unsigned short* p_att_bf   = (unsigned short*)alloc((size_t)kB * kL * kH / 2);   // 12.8 MB
    unsigned short* ctx_hi     = (unsigned short*)alloc((size_t)kH * kF / 2);
    unsigned short* logit_hi   = (unsigned short*)alloc((size_t)kV * kR / 2);
    unsigned short* embed_bf   = (unsigned short*)alloc((size_t)kV * kEp / 2);
    unsigned short* i2h_bf     = (unsigned short*)alloc((size_t)5 * kR * kEp / 2);
    unsigned short* wcat_bf    = (unsigned short*)alloc((size_t)kNcat * kR / 2);     // 11.5 MB
    unsigned short* a2c_bf     = (unsigned short*)alloc((size_t)2 * kR * kF / 2);    // 8.4 MB
    unsigned short* h_all_bf   = (unsigned short*)alloc((size_t)kB * kT * kR / 2);
    unsigned short* h_zero_bf  = (unsigned short*)alloc((size_t)kB * kR / 2);
    unsigned short* i2h_pre_bf = (unsigned short*)alloc((size_t)kB * kT * 5 * kR / 2); // 13 MB
    float* part56  = alloc((size_t)2 * kB * kNcat);      // 2.9 MB
    float* cbuf    = alloc((size_t)kB * kR);

    hipMemsetAsync(cbuf, 0, (size_t)kB * kR * sizeof(float), stream);
    hipMemsetAsync(h_zero_bf, 0, (size_t)kB * kR * sizeof(unsigned short), stream);
    hipMemsetAsync(embed_bf, 0, (size_t)kV * kEp * sizeof(unsigned short), stream);
    hipMemsetAsync(i2h_bf,   0, (size_t)5 * kR * kEp * sizeof(unsigned short), stream);

    // one-time conversions / packs
    conv_hi_kernel<<<2048, 256, 0, stream>>>(att_feats, af_bf, kB * kL * kF / 4);
    conv_hi_kernel<<<512, 256, 0, stream>>>(ctx2att_w, ctx_hi, kH * kF / 4);
    conv_hi_kernel<<<2048, 256, 0, stream>>>(logit_w, logit_hi, kV * kR / 4);
    conv_pad300_kernel<<<1024, 256, 0, stream>>>(embed_w, embed_bf, kV);
    conv_pad300_kernel<<<512, 256, 0, stream>>>(i2h_w, i2h_bf, 5 * kR);
    conv_hi_kernel<<<1024, 256, 0, stream>>>(h2h_w, wcat_bf, 5 * kR * kR / 4);
    conv_hi_kernel<<<256, 256, 0, stream>>>(h2att_w, wcat_bf + (size_t)5 * kR * kR, kH * kR / 4);
    conv_hi_kernel<<<1024, 256, 0, stream>>>(a2c_w, a2c_bf, 2 * kR * kF / 4);

    // p_att = att_feats @ ctx2att_w.T + b -> bf16   (12544 x 512, K=2048)
    gemm_glds_kernel<true, false><<<dim3(kH / 128, kB * kL / 128), 256, 0, stream>>>(
        af_bf, kF, ctx_hi, kF, ctx2att_b, p_att_bf, kH, kB * kL, kH, kF, nullptr);

    // i2h_pre = embed[seq] @ i2h_w.T + b -> bf16   (1280 x 5120, K=320 padded)
    gemm_glds_kernel<true, true><<<dim3(5 * kR / 128, kB * kT / 128), 256, 0, stream>>>(
        embed_bf, kEp, i2h_bf, kEp, i2h_b, i2h_pre_bf, 5 * kR, kB * kT, 5 * kR, kEp, seq);

    // pre_a2c = att_feats @ a2c_w.T + a2c_b -> bf16  (12544 x 2048, K=2048)
    gemm_glds_kernel<true, false><<<dim3(kF / 128, kB * kL / 128), 256, 0, stream>>>(
        af_bf, kF, a2c_bf, kF, a2c_b, pre_bf, kF, kB * kL, kF, kF, nullptr);

    // 20-step recurrence: 2 launches per step
    for (int t = 0; t < kT; ++t) {
        const unsigned short* h_prev = (t == 0) ? h_zero_bf : (h_all_bf + (size_t)(t - 1) * kR);
        const int lda_h = (t == 0) ? kR : kT * kR;

        // part56 = h_prev @ [h2h | h2att].T   (64 x 5632, K=1024, ks=2)
        gemm_sums_kernel<<<dim3(kNcat / 64, 2), 256, 0, stream>>>(
            h_prev, lda_h, wcat_bf, kR, part56, kNcat, kR / 2);

        att_step_kernel<<<dim3(4, kB), 256, 0, stream>>>(
            part56, h2att_b, p_att_bf, alpha_w, pre_bf, i2h_pre_bf, h2h_b,
            cbuf, h_all_bf, t);
    }

    // logits = h_all @ logit_w.T + b -> out fp32  (1280 x 12001, K=1024)
    gemm_glds_kernel<false, false><<<dim3((kV + 127) / 128, kB * kT / 128), 256, 0, stream>>>(
        h_all_bf, kR, logit_hi, kR, logit_b, out, kV, kB * kT, kV, kR, nullptr);

    log_softmax_kernel<<<dim3(kB * kT), 256, 0, stream>>>(out);
}

// Round 15
// 1794.359 us; speedup vs baseline: 2.1126x; 1.0300x over previous
//
#include <hip/hip_runtime.h>
#include <math.h>

namespace {
constexpr int kV = 12001;
constexpr int kE = 300;
constexpr int kEp = 320;   // padded K for i2h
constexpr int kR = 1024;
constexpr int kH = 512;
constexpr int kF = 2048;
constexpr int kB = 64;
constexpr int kT = 20;
constexpr int kL = 196;
constexpr int kNcat = 5 * kR + kH;   // 5632: [h2h | h2att]
constexpr int kKS = 4;               // K-split for gemm_sums
}

typedef __attribute__((ext_vector_type(8))) short short8;
typedef __attribute__((ext_vector_type(4))) float f32x4;

#define GLB_PTR(p) ((const __attribute__((address_space(1))) void*)(p))
#define LDS_PTR(p) ((__attribute__((address_space(3))) void*)(p))

__device__ __forceinline__ unsigned short f2bf(float f) {
    unsigned u = __builtin_bit_cast(unsigned, f);
    u = (u + 0x7fffu + ((u >> 16) & 1u)) >> 16;
    return (unsigned short)u;
}
__device__ __forceinline__ float bf2f(unsigned short h) {
    unsigned u = ((unsigned)h) << 16;
    return __builtin_bit_cast(float, u);
}
__device__ __forceinline__ float fast_tanh(float x) {
    x = fminf(15.f, fmaxf(-15.f, x));
    const float e = __expf(2.f * x);
    return (e - 1.f) / (e + 1.f);
}
__device__ __forceinline__ float fast_sig(float x) {
    return 1.f / (1.f + __expf(-x));
}

// bijective XCD-chunk swizzle (m204): contiguous chunk of blocks per XCD
__device__ __forceinline__ int xcd_swizzle(int orig, int nwg) {
    const int q = nwg >> 3, r = nwg & 7;
    const int xcd = orig & 7, lo = orig >> 3;
    return (xcd < r ? xcd * (q + 1) : r * (q + 1) + (xcd - r) * q) + lo;
}

// ---------------------------------------------------------------------------
// One-shot conversion/pack/zero kernel: all fp32->bf16 jobs + padded packs +
// zero-fills, partitioned by global index range.
// ---------------------------------------------------------------------------
__global__ __launch_bounds__(256)
void conv_all_kernel(const float* __restrict__ af_in,  unsigned short* __restrict__ af_out,
                     const float* __restrict__ ctx_in, unsigned short* __restrict__ ctx_out,
                     const float* __restrict__ lg_in,  unsigned short* __restrict__ lg_out,
                     const float* __restrict__ h2h_in, unsigned short* __restrict__ h2h_out,
                     const float* __restrict__ h2a_in, unsigned short* __restrict__ h2a_out,
                     const float* __restrict__ a2c_in, unsigned short* __restrict__ a2c_out,
                     const float* __restrict__ emb_in, unsigned short* __restrict__ emb_out,
                     const float* __restrict__ i2h_in, unsigned short* __restrict__ i2h_out,
                     unsigned short* __restrict__ hz_out, float* __restrict__ cb_out)
{
    constexpr int c0 = kB * kL * kF / 4;                 // af
    constexpr int c1 = c0 + kH * kF / 4;                 // ctx
    constexpr int c2 = c1 + kV * kR / 4;                 // logit
    constexpr int c3 = c2 + 5 * kR * kR / 4;             // h2h
    constexpr int c4 = c3 + kH * kR / 4;                 // h2att
    constexpr int c5 = c4 + 2 * kR * kF / 4;             // a2c
    constexpr int c6 = c5 + kV * 80;                     // embed pad (80 grp/row)
    constexpr int c7 = c6 + 5 * kR * 80;                 // i2h pad
    constexpr int c8 = c7 + kB * kR / 4;                 // h_zero
    constexpr int c9 = c8 + kB * kR / 4;                 // cbuf zero

    for (int i = blockIdx.x * 256 + threadIdx.x; i < c9; i += gridDim.x * 256) {
        if (i < c5) {
            const float* in; unsigned short* out; int l;
            if      (i < c0) { in = af_in;  out = af_out;  l = i; }
            else if (i < c1) { in = ctx_in; out = ctx_out; l = i - c0; }
            else if (i < c2) { in = lg_in;  out = lg_out;  l = i - c1; }
            else if (i < c3) { in = h2h_in; out = h2h_out; l = i - c2; }
            else if (i < c4) { in = h2a_in; out = h2a_out; l = i - c3; }
            else             { in = a2c_in; out = a2c_out; l = i - c4; }
            const float4 v = ((const float4*)in)[l];
            ushort4 o;
            o.x = f2bf(v.x); o.y = f2bf(v.y); o.z = f2bf(v.z); o.w = f2bf(v.w);
            ((ushort4*)out)[l] = o;
        } else if (i < c7) {
            const float* in; unsigned short* out; int l;
            if (i < c6) { in = emb_in; out = emb_out; l = i - c5; }
            else        { in = i2h_in; out = i2h_out; l = i - c6; }
            const int row = l / 80, c = l - row * 80;
            ushort4 o = make_ushort4(0, 0, 0, 0);
            if (c < 75) {
                const float4 v = *(const float4*)(in + (size_t)row * kE + c * 4);
                o.x = f2bf(v.x); o.y = f2bf(v.y); o.z = f2bf(v.z); o.w = f2bf(v.w);
            }
            *(ushort4*)(out + (size_t)row * kEp + c * 4) = o;
        } else if (i < c8) {
            ((ushort4*)hz_out)[i - c7] = make_ushort4(0, 0, 0, 0);
        } else {
            ((float4*)cb_out)[i - c8] = make_float4(0.f, 0.f, 0.f, 0.f);
        }
    }
}

// ---------------------------------------------------------------------------
// Pure-bf16 MFMA GEMM, width-16 global_load_lds staging, XCD-swizzled 1D grid.
// nfirst=1: bx fastest (blocks sharing A-rows colocate); 0: by fastest.
// ---------------------------------------------------------------------------
template<bool OUT_BF16, bool GATHER>
__global__ __launch_bounds__(256)
void gemm_glds_kernel(const unsigned short* __restrict__ Ah, int lda,
                      const unsigned short* __restrict__ Wh, int ldw,
                      const float* __restrict__ bias,
                      void* __restrict__ Cp, int ldc,
                      int M, int N, int K,
                      const int* __restrict__ ridx,
                      int nbx, int nby, int nfirst)
{
    __shared__ __align__(16) unsigned short sA[128 * 32];
    __shared__ __align__(16) unsigned short sW[128 * 32];
    const int tid = threadIdx.x;
    const int swz = xcd_swizzle(blockIdx.x, nbx * nby);
    int bx, by;
    if (nfirst) { bx = swz % nbx; by = swz / nbx; }
    else        { by = swz % nby; bx = swz / nby; }
    const int m0 = by * 128;
    const int n0 = bx * 128;
    const int wave = tid >> 6, lane = tid & 63;
    const int wm = wave >> 1, wn = wave & 1;
    const int lrow = lane & 15, lkg = lane >> 4;

    const int rsub   = lane >> 2;        // 0..15 row within 16-row issue
    const int cchunk = (lane & 3) * 8;   // element offset of 8-elem chunk

    f32x4 acc[4][4];
    #pragma unroll
    for (int mi = 0; mi < 4; ++mi)
        #pragma unroll
        for (int ni = 0; ni < 4; ++ni)
            acc[mi][ni] = (f32x4){0.f, 0.f, 0.f, 0.f};

    for (int k0 = 0; k0 < K; k0 += 32) {
        #pragma unroll
        for (int j = 0; j < 2; ++j) {
            const int mrow = m0 + wave * 32 + j * 16 + rsub;
            const int row = GATHER ? ridx[mrow] : mrow;
            __builtin_amdgcn_global_load_lds(
                GLB_PTR(Ah + (size_t)row * lda + k0 + cchunk),
                LDS_PTR(sA + wave * 1024 + j * 512), 16, 0, 0);
        }
        #pragma unroll
        for (int j = 0; j < 2; ++j) {
            const int n = n0 + wave * 32 + j * 16 + rsub;
            __builtin_amdgcn_global_load_lds(
                GLB_PTR(Wh + (size_t)n * ldw + k0 + cchunk),
                LDS_PTR(sW + wave * 1024 + j * 512), 16, 0, 0);
        }
        __syncthreads();

        short8 af[4], wf[4];
        #pragma unroll
        for (int mi = 0; mi < 4; ++mi)
            af[mi] = *(const short8*)(sA + (wm * 64 + mi * 16 + lrow) * 32 + lkg * 8);
        #pragma unroll
        for (int ni = 0; ni < 4; ++ni)
            wf[ni] = *(const short8*)(sW + (wn * 64 + ni * 16 + lrow) * 32 + lkg * 8);
        #pragma unroll
        for (int mi = 0; mi < 4; ++mi)
            #pragma unroll
            for (int ni = 0; ni < 4; ++ni)
                acc[mi][ni] = __builtin_amdgcn_mfma_f32_16x16x32_bf16(af[mi], wf[ni], acc[mi][ni], 0, 0, 0);
        __syncthreads();
    }

    // epilogue: row = (lane>>4)*4 + reg, col = lane&15 (m89-verified layout)
    #pragma unroll
    for (int mi = 0; mi < 4; ++mi) {
        const int mbase = m0 + wm * 64 + mi * 16 + lkg * 4;
        #pragma unroll
        for (int ni = 0; ni < 4; ++ni) {
            const int n = n0 + wn * 64 + ni * 16 + lrow;
            if (n >= N) continue;
            const float bb = bias ? bias[n] : 0.f;
            #pragma unroll
            for (int r = 0; r < 4; ++r) {
                const int m = mbase + r;
                const float v = acc[mi][ni][r] + bb;
                if (OUT_BF16) ((unsigned short*)Cp)[(size_t)m * ldc + n] = f2bf(v);
                else          ((float*)Cp)[(size_t)m * ldc + n] = v;
            }
        }
    }
}

// ---------------------------------------------------------------------------
// Small-M sums GEMM with glds staging: part[ks][64][N] = A(64xK)@W(NxK).T
// BM=64, BN=64, BK=32. grid (N/64, kKS). Kblk = Ktot/kKS.
// ---------------------------------------------------------------------------
__global__ __launch_bounds__(256)
void gemm_sums_kernel(const unsigned short* __restrict__ A, int lda,
                      const unsigned short* __restrict__ W, int ldw,
                      float* __restrict__ part, int N, int Kblk)
{
    __shared__ __align__(16) unsigned short sA[64 * 32];
    __shared__ __align__(16) unsigned short sW[64 * 32];
    const int tid = threadIdx.x;
    const int n0 = blockIdx.x * 64;
    const int ks = blockIdx.y;
    const int kbeg = ks * Kblk;
    const int wave = tid >> 6, lane = tid & 63;
    const int lrow = lane & 15, lkg = lane >> 4;
    const int rsub   = lane >> 2;
    const int cchunk = (lane & 3) * 8;

    f32x4 acc[4];
    #pragma unroll
    for (int mi = 0; mi < 4; ++mi) acc[mi] = (f32x4){0.f, 0.f, 0.f, 0.f};

    for (int k0 = kbeg; k0 < kbeg + Kblk; k0 += 32) {
        __builtin_amdgcn_global_load_lds(
            GLB_PTR(A + (size_t)(wave * 16 + rsub) * lda + k0 + cchunk),
            LDS_PTR(sA + wave * 512), 16, 0, 0);
        __builtin_amdgcn_global_load_lds(
            GLB_PTR(W + (size_t)(n0 + wave * 16 + rsub) * ldw + k0 + cchunk),
            LDS_PTR(sW + wave * 512), 16, 0, 0);
        __syncthreads();
        const short8 wf = *(const short8*)(sW + (wave * 16 + lrow) * 32 + lkg * 8);
        #pragma unroll
        for (int mi = 0; mi < 4; ++mi) {
            const short8 af = *(const short8*)(sA + (mi * 16 + lrow) * 32 + lkg * 8);
            acc[mi] = __builtin_amdgcn_mfma_f32_16x16x32_bf16(af, wf, acc[mi], 0, 0, 0);
        }
        __syncthreads();
    }

    float* po = part + (size_t)ks * 64 * N;
    const int n = n0 + wave * 16 + lrow;
    #pragma unroll
    for (int mi = 0; mi < 4; ++mi)
        #pragma unroll
        for (int rr = 0; rr < 4; ++rr)
            po[(size_t)(mi * 16 + lkg * 4 + rr) * N + n] = acc[mi][rr];
}

// ---------------------------------------------------------------------------
// Step kernel: e + softmax (4x redundant per fc) + paired readout of
// pre_a2c cols (r, 1024+r) + full gates -> cbuf, h_all_bf[t].
// grid (4 fc, 64 b), 256 thr; thread owns r = fc*256 + tid. kKS part slices.
// ---------------------------------------------------------------------------
__global__ __launch_bounds__(256)
void att_step_kernel(const float* __restrict__ part56,
                     const float* __restrict__ h2att_b,
                     const unsigned short* __restrict__ p_att_bf,
                     const float* __restrict__ alpha_w,
                     const unsigned short* __restrict__ pre_bf,
                     const unsigned short* __restrict__ i2h_pre_bf,
                     const float* __restrict__ h2h_b,
                     float* __restrict__ cbuf,
                     unsigned short* __restrict__ h_all_bf,
                     int t)
{
    const int fc = blockIdx.x, b = blockIdx.y;
    const int tid = threadIdx.x;
    const int wave = tid >> 6, lane = tid & 63;
    __shared__ float ahT[8][64];
    __shared__ float awT[8][64];
    __shared__ float esm[kL];
    __shared__ float wsm[kL];
    __shared__ float red2[2];

    for (int i = tid; i < kH; i += 256) {
        const size_t base = (size_t)b * kNcat + 5 * kR + i;
        float v = h2att_b[i];
        #pragma unroll
        for (int s = 0; s < kKS; ++s) v += part56[(size_t)s * 64 * kNcat + base];
        ahT[i & 7][i >> 3] = v;
        awT[i & 7][i >> 3] = alpha_w[i];
    }
    __syncthreads();

    // e: 4 waves, wave handles l = wave, wave+4, ...
    for (int l = wave; l < kL; l += 4) {
        const short8 pv = *(const short8*)(p_att_bf + ((size_t)b * kL + l) * kH + lane * 8);
        float a = 0.f;
        #pragma unroll
        for (int j = 0; j < 8; ++j)
            a += fast_tanh(bf2f(((const unsigned short*)&pv)[j]) + ahT[j][lane]) * awT[j][lane];
        #pragma unroll
        for (int off = 32; off; off >>= 1) a += __shfl_xor(a, off, 64);
        if (lane == 0) esm[l] = a;
    }
    __syncthreads();

    if (wave == 0) {
        float m = -1e30f;
        for (int l = lane; l < kL; l += 64) m = fmaxf(m, esm[l]);
        #pragma unroll
        for (int off = 32; off; off >>= 1) m = fmaxf(m, __shfl_xor(m, off, 64));
        float ssum = 0.f;
        for (int l = lane; l < kL; l += 64) ssum += __expf(esm[l] - m);
        #pragma unroll
        for (int off = 32; off; off >>= 1) ssum += __shfl_xor(ssum, off, 64);
        if (lane == 0) { red2[0] = m; red2[1] = 1.f / ssum; }
    }
    __syncthreads();
    if (tid < kL) wsm[tid] = __expf(esm[tid] - red2[0]) * red2[1];
    __syncthreads();

    // paired readout: itr cols r and 1024+r  (pre_a2c includes a2c_b; sum_l w = 1)
    const int r = fc * 256 + tid;
    float s3 = 0.f, s4 = 0.f;
    const unsigned short* base = pre_bf + (size_t)b * kL * kF + r;
    #pragma unroll 8
    for (int l = 0; l < kL; ++l) {
        const float wl = wsm[l];
        s3 += wl * bf2f(base[(size_t)l * kF]);
        s4 += wl * bf2f(base[(size_t)l * kF + kR]);
    }

    // gates
    const unsigned short* ib = i2h_pre_bf + (size_t)(b * kT + t) * (5 * kR);
    float S0 = bf2f(ib[r])          + h2h_b[r];
    float S1 = bf2f(ib[kR + r])     + h2h_b[kR + r];
    float S2 = bf2f(ib[2 * kR + r]) + h2h_b[2 * kR + r];
    float S3 = bf2f(ib[3 * kR + r]) + h2h_b[3 * kR + r] + s3;
    float S4 = bf2f(ib[4 * kR + r]) + h2h_b[4 * kR + r] + s4;
    #pragma unroll
    for (int s = 0; s < kKS; ++s) {
        const float* p = part56 + (size_t)s * 64 * kNcat + (size_t)b * kNcat;
        S0 += p[r];
        S1 += p[kR + r];
        S2 += p[2 * kR + r];
        S3 += p[3 * kR + r];
        S4 += p[4 * kR + r];
    }

    const float ing = fast_sig(S0);
    const float fg  = fast_sig(S1);
    const float og  = fast_sig(S2);
    const float gg  = fmaxf(S3, S4);
    const int idx = b * kR + r;
    const float nc = fg * cbuf[idx] + ing * gg;
    const float nh = og * fast_tanh(nc);
    cbuf[idx] = nc;
    h_all_bf[(size_t)(b * kT + t) * kR + r] = f2bf(nh);
}

// ---------------------------------------------------------------------------
// in-place log_softmax over V; one block per row. Online max/sum.
// ---------------------------------------------------------------------------
__global__ __launch_bounds__(256)
void log_softmax_kernel(float* __restrict__ out)
{
    __shared__ float mred[256];
    __shared__ float sred[256];
    const int tid = threadIdx.x;
    float* row = out + (size_t)blockIdx.x * kV;

    float m = -1e30f, s = 0.f;
    for (int v = tid; v < kV; v += 256) {
        const float x = row[v];
        if (x > m) { s = s * __expf(m - x) + 1.f; m = x; }
        else        s += __expf(x - m);
    }
    mred[tid] = m; sred[tid] = s; __syncthreads();
    for (int st = 128; st > 0; st >>= 1) {
        if (tid < st) {
            const float m2 = mred[tid + st], s2 = sred[tid + st];
            const float M = fmaxf(mred[tid], m2);
            sred[tid] = sred[tid] * __expf(mred[tid] - M) + s2 * __expf(m2 - M);
            mred[tid] = M;
        }
        __syncthreads();
    }
    const float ls = mred[0] + logf(sred[0]);
    for (int v = tid; v < kV; v += 256) row[v] -= ls;
}

extern "C" void kernel_launch(void* const* d_in, const int* in_sizes, int n_in,
                              void* d_out, int out_size, void* d_ws, size_t ws_size,
                              hipStream_t stream)
{
    const int*   seq       = (const int*)  d_in[0];
    const float* att_feats = (const float*)d_in[1];
    const float* embed_w   = (const float*)d_in[2];
    const float* ctx2att_w = (const float*)d_in[3];
    const float* ctx2att_b = (const float*)d_in[4];
    const float* h2att_w   = (const float*)d_in[5];
    const float* h2att_b   = (const float*)d_in[6];
    const float* alpha_w   = (const float*)d_in[7];
    const float* i2h_w     = (const float*)d_in[9];
    const float* i2h_b     = (const float*)d_in[10];
    const float* h2h_w     = (const float*)d_in[11];
    const float* h2h_b     = (const float*)d_in[12];
    const float* a2c_w     = (const float*)d_in[13];
    const float* a2c_b     = (const float*)d_in[14];
    const float* logit_w   = (const float*)d_in[15];
    const float* logit_b   = (const float*)d_in[16];
    float* out = (float*)d_out;

    float* ws = (float*)d_ws;
    size_t off = 0;
    auto alloc = [&](size_t nf) { float* p = ws + off; off += (nf + 3) & ~(size_t)3; return p; };

    unsigned short* af_bf      = (unsigned short*)alloc((size_t)kB * kL * kF / 2);   // 51 MB
    unsigned short* pre_bf     = (unsigned short*)alloc((size_t)kB * kL * kF / 2);   // 51 MB
    unsigned short* p_att_bf   = (unsigned short*)alloc((size_t)kB * kL * kH / 2);   // 12.8 MB
    unsigned short* ctx_hi     = (unsigned short*)alloc((size_t)kH * kF / 2);
    unsigned short* logit_hi   = (unsigned short*)alloc((size_t)kV * kR / 2);
    unsigned short* embed_bf   = (unsigned short*)alloc((size_t)kV * kEp / 2);
    unsigned short* i2h_bf     = (unsigned short*)alloc((size_t)5 * kR * kEp / 2);
    unsigned short* wcat_bf    = (unsigned short*)alloc((size_t)kNcat * kR / 2);     // 11.5 MB
    unsigned short* a2c_bf     = (unsigned short*)alloc((size_t)2 * kR * kF / 2);    // 8.4 MB
    unsigned short* h_all_bf   = (unsigned short*)alloc((size_t)kB * kT * kR / 2);
    unsigned short* h_zero_bf  = (unsigned short*)alloc((size_t)kB * kR / 2);
    unsigned short* i2h_pre_bf = (unsigned short*)alloc((size_t)kB * kT * 5 * kR / 2); // 13 MB
    float* part56  = alloc((size_t)kKS * kB * kNcat);    // 5.8 MB
    float* cbuf    = alloc((size_t)kB * kR);

    // all conversions + pads + zero-fills in ONE launch
    conv_all_kernel<<<4096, 256, 0, stream>>>(
        att_feats, af_bf, ctx2att_w, ctx_hi, logit_w, logit_hi,
        h2h_w, wcat_bf, h2att_w, wcat_bf + (size_t)5 * kR * kR,
        a2c_w, a2c_bf, embed_w, embed_bf, i2h_w, i2h_bf,
        h_zero_bf, cbuf);

    // p_att = att_feats @ ctx2att_w.T + b -> bf16   (12544 x 512, K=2048)
    gemm_glds_kernel<true, false><<<dim3(4 * 98), 256, 0, stream>>>(
        af_bf, kF, ctx_hi, kF, ctx2att_b, p_att_bf, kH, kB * kL, kH, kF, nullptr,
        4, 98, 1);

    // i2h_pre = embed[seq] @ i2h_w.T + b -> bf16   (1280 x 5120, K=320 padded)
    gemm_glds_kernel<true, true><<<dim3(40 * 10), 256, 0, stream>>>(
        embed_bf, kEp, i2h_bf, kEp, i2h_b, i2h_pre_bf, 5 * kR, kB * kT, 5 * kR, kEp, seq,
        40, 10, 1);

    // pre_a2c = att_feats @ a2c_w.T + a2c_b -> bf16  (12544 x 2048, K=2048)
    gemm_glds_kernel<true, false><<<dim3(16 * 98), 256, 0, stream>>>(
        af_bf, kF, a2c_bf, kF, a2c_b, pre_bf, kF, kB * kL, kF, kF, nullptr,
        16, 98, 1);

    // 20-step recurrence: 2 launches per step
    for (int t = 0; t < kT; ++t) {
        const unsigned short* h_prev = (t == 0) ? h_zero_bf : (h_all_bf + (size_t)(t - 1) * kR);
        const int lda_h = (t == 0) ? kR : kT * kR;

        // part56 = h_prev @ [h2h | h2att].T   (64 x 5632, K=1024, ks=4)
        gemm_sums_kernel<<<dim3(kNcat / 64, kKS), 256, 0, stream>>>(
            h_prev, lda_h, wcat_bf, kR, part56, kNcat, kR / kKS);

        att_step_kernel<<<dim3(4, kB), 256, 0, stream>>>(
            part56, h2att_b, p_att_bf, alpha_w, pre_bf, i2h_pre_bf, h2h_b,
            cbuf, h_all_bf, t);
    }

    // logits = h_all @ logit_w.T + b -> out fp32  (1280 x 12001, K=1024)
    gemm_glds_kernel<false, false><<<dim3(94 * 10), 256, 0, stream>>>(
        h_all_bf, kR, logit_hi, kR, logit_b, out, kV, kB * kT, kV, kR, nullptr,
        94, 10, 0);

    log_softmax_kernel<<<dim3(kB * kT), 256, 0, stream>>>(out);
}

// Round 16
// 1248.046 us; speedup vs baseline: 3.0373x; 1.4377x over previous
//
#include <hip/hip_runtime.h>
#include <math.h>

namespace {
constexpr int kV = 12001;
constexpr int kE = 300;
constexpr int kEp = 320;   // padded K for i2h
constexpr int kR = 1024;
constexpr int kH = 512;
constexpr int kF = 2048;
constexpr int kB = 64;
constexpr int kT = 20;
constexpr int kL = 196;
constexpr int kNcat = 5 * kR + kH;   // 5632: [h2h | h2att]
constexpr int kKS = 4;               // K-split for gemm_sums
constexpr int kNc2 = kH + kF;        // 2560: [p_att | pre_a2c] combined cols
}

typedef __attribute__((ext_vector_type(8))) short short8;
typedef __attribute__((ext_vector_type(4))) float f32x4;

#define GLB_PTR(p) ((const __attribute__((address_space(1))) void*)(p))
#define LDS_PTR(p) ((__attribute__((address_space(3))) void*)(p))

__device__ __forceinline__ unsigned short f2bf(float f) {
    unsigned u = __builtin_bit_cast(unsigned, f);
    u = (u + 0x7fffu + ((u >> 16) & 1u)) >> 16;
    return (unsigned short)u;
}
__device__ __forceinline__ float bf2f(unsigned short h) {
    unsigned u = ((unsigned)h) << 16;
    return __builtin_bit_cast(float, u);
}
__device__ __forceinline__ float fast_tanh(float x) {
    x = fminf(15.f, fmaxf(-15.f, x));
    const float e = __expf(2.f * x);
    return (e - 1.f) / (e + 1.f);
}
__device__ __forceinline__ float fast_sig(float x) {
    return 1.f / (1.f + __expf(-x));
}

// bijective XCD-chunk swizzle (m204)
__device__ __forceinline__ int xcd_swizzle(int orig, int nwg) {
    const int q = nwg >> 3, r = nwg & 7;
    const int xcd = orig & 7, lo = orig >> 3;
    return (xcd < r ? xcd * (q + 1) : r * (q + 1) + (xcd - r) * q) + lo;
}

// ---------------------------------------------------------------------------
// One-shot conversion/pack/zero kernel (all jobs partitioned by index range).
// wcomb = [ctx2att_w (512 rows) ; a2c_w (2048 rows)], bias_comb likewise.
// ---------------------------------------------------------------------------
__global__ __launch_bounds__(256)
void conv_all_kernel(const float* __restrict__ af_in,  unsigned short* __restrict__ af_out,
                     const float* __restrict__ ctx_in,
                     const float* __restrict__ lg_in,  unsigned short* __restrict__ lg_out,
                     const float* __restrict__ h2h_in, unsigned short* __restrict__ h2h_out,
                     const float* __restrict__ h2a_in, unsigned short* __restrict__ h2a_out,
                     const float* __restrict__ a2c_in, unsigned short* __restrict__ wcomb_out,
                     const float* __restrict__ emb_in, unsigned short* __restrict__ emb_out,
                     const float* __restrict__ i2h_in, unsigned short* __restrict__ i2h_out,
                     unsigned short* __restrict__ hz_out, float* __restrict__ cb_out,
                     const float* __restrict__ ctxb_in, const float* __restrict__ a2cb_in,
                     float* __restrict__ biasc_out)
{
    constexpr int c0 = kB * kL * kF / 4;                 // af
    constexpr int c1 = c0 + kH * kF / 4;                 // ctx -> wcomb rows 0-511
    constexpr int c2 = c1 + kV * kR / 4;                 // logit
    constexpr int c3 = c2 + 5 * kR * kR / 4;             // h2h -> wcat
    constexpr int c4 = c3 + kH * kR / 4;                 // h2att -> wcat tail
    constexpr int c5 = c4 + 2 * kR * kF / 4;             // a2c -> wcomb rows 512+
    constexpr int c6 = c5 + kV * 80;                     // embed pad
    constexpr int c7 = c6 + 5 * kR * 80;                 // i2h pad
    constexpr int c8 = c7 + kB * kR / 4;                 // h_zero
    constexpr int c9 = c8 + kB * kR / 4;                 // cbuf zero
    constexpr int c10 = c9 + kNc2 / 4;                   // bias_comb copy

    for (int i = blockIdx.x * 256 + threadIdx.x; i < c10; i += gridDim.x * 256) {
        if (i < c5) {
            const float* in; unsigned short* out; int l;
            if      (i < c0) { in = af_in;  out = af_out;                      l = i; }
            else if (i < c1) { in = ctx_in; out = wcomb_out;                   l = i - c0; }
            else if (i < c2) { in = lg_in;  out = lg_out;                      l = i - c1; }
            else if (i < c3) { in = h2h_in; out = h2h_out;                     l = i - c2; }
            else if (i < c4) { in = h2a_in; out = h2a_out;                     l = i - c3; }
            else             { in = a2c_in; out = wcomb_out + (size_t)kH * kF; l = i - c4; }
            const float4 v = ((const float4*)in)[l];
            ushort4 o;
            o.x = f2bf(v.x); o.y = f2bf(v.y); o.z = f2bf(v.z); o.w = f2bf(v.w);
            ((ushort4*)out)[l] = o;
        } else if (i < c7) {
            const float* in; unsigned short* out; int l;
            if (i < c6) { in = emb_in; out = emb_out; l = i - c5; }
            else        { in = i2h_in; out = i2h_out; l = i - c6; }
            const int row = l / 80, c = l - row * 80;
            ushort4 o = make_ushort4(0, 0, 0, 0);
            if (c < 75) {
                const float4 v = *(const float4*)(in + (size_t)row * kE + c * 4);
                o.x = f2bf(v.x); o.y = f2bf(v.y); o.z = f2bf(v.z); o.w = f2bf(v.w);
            }
            *(ushort4*)(out + (size_t)row * kEp + c * 4) = o;
        } else if (i < c8) {
            ((ushort4*)hz_out)[i - c7] = make_ushort4(0, 0, 0, 0);
        } else if (i < c9) {
            ((float4*)cb_out)[i - c8] = make_float4(0.f, 0.f, 0.f, 0.f);
        } else {
            const int l = i - c9;   // 0..639
            float4 v;
            if (l < kH / 4) v = ((const float4*)ctxb_in)[l];
            else            v = ((const float4*)a2cb_in)[l - kH / 4];
            ((float4*)biasc_out)[l] = v;
        }
    }
}

// ---------------------------------------------------------------------------
// Pure-bf16 MFMA GEMM, width-16 global_load_lds staging, XCD-swizzled 1D grid.
// ---------------------------------------------------------------------------
template<bool OUT_BF16, bool GATHER>
__global__ __launch_bounds__(256)
void gemm_glds_kernel(const unsigned short* __restrict__ Ah, int lda,
                      const unsigned short* __restrict__ Wh, int ldw,
                      const float* __restrict__ bias,
                      void* __restrict__ Cp, int ldc,
                      int M, int N, int K,
                      const int* __restrict__ ridx,
                      int nbx, int nby, int nfirst)
{
    __shared__ __align__(16) unsigned short sA[128 * 32];
    __shared__ __align__(16) unsigned short sW[128 * 32];
    const int tid = threadIdx.x;
    const int swz = xcd_swizzle(blockIdx.x, nbx * nby);
    int bx, by;
    if (nfirst) { bx = swz % nbx; by = swz / nbx; }
    else        { by = swz % nby; bx = swz / nby; }
    const int m0 = by * 128;
    const int n0 = bx * 128;
    const int wave = tid >> 6, lane = tid & 63;
    const int wm = wave >> 1, wn = wave & 1;
    const int lrow = lane & 15, lkg = lane >> 4;

    const int rsub   = lane >> 2;
    const int cchunk = (lane & 3) * 8;

    f32x4 acc[4][4];
    #pragma unroll
    for (int mi = 0; mi < 4; ++mi)
        #pragma unroll
        for (int ni = 0; ni < 4; ++ni)
            acc[mi][ni] = (f32x4){0.f, 0.f, 0.f, 0.f};

    for (int k0 = 0; k0 < K; k0 += 32) {
        #pragma unroll
        for (int j = 0; j < 2; ++j) {
            const int mrow = m0 + wave * 32 + j * 16 + rsub;
            const int row = GATHER ? ridx[mrow] : mrow;
            __builtin_amdgcn_global_load_lds(
                GLB_PTR(Ah + (size_t)row * lda + k0 + cchunk),
                LDS_PTR(sA + wave * 1024 + j * 512), 16, 0, 0);
        }
        #pragma unroll
        for (int j = 0; j < 2; ++j) {
            const int n = n0 + wave * 32 + j * 16 + rsub;
            __builtin_amdgcn_global_load_lds(
                GLB_PTR(Wh + (size_t)n * ldw + k0 + cchunk),
                LDS_PTR(sW + wave * 1024 + j * 512), 16, 0, 0);
        }
        __syncthreads();

        short8 af[4], wf[4];
        #pragma unroll
        for (int mi = 0; mi < 4; ++mi)
            af[mi] = *(const short8*)(sA + (wm * 64 + mi * 16 + lrow) * 32 + lkg * 8);
        #pragma unroll
        for (int ni = 0; ni < 4; ++ni)
            wf[ni] = *(const short8*)(sW + (wn * 64 + ni * 16 + lrow) * 32 + lkg * 8);
        #pragma unroll
        for (int mi = 0; mi < 4; ++mi)
            #pragma unroll
            for (int ni = 0; ni < 4; ++ni)
                acc[mi][ni] = __builtin_amdgcn_mfma_f32_16x16x32_bf16(af[mi], wf[ni], acc[mi][ni], 0, 0, 0);
        __syncthreads();
    }

    // epilogue: row = (lane>>4)*4 + reg, col = lane&15 (m89-verified layout)
    #pragma unroll
    for (int mi = 0; mi < 4; ++mi) {
        const int mbase = m0 + wm * 64 + mi * 16 + lkg * 4;
        #pragma unroll
        for (int ni = 0; ni < 4; ++ni) {
            const int n = n0 + wn * 64 + ni * 16 + lrow;
            if (n >= N) continue;
            const float bb = bias ? bias[n] : 0.f;
            #pragma unroll
            for (int r = 0; r < 4; ++r) {
                const int m = mbase + r;
                const float v = acc[mi][ni][r] + bb;
                if (OUT_BF16) ((unsigned short*)Cp)[(size_t)m * ldc + n] = f2bf(v);
                else          ((float*)Cp)[(size_t)m * ldc + n] = v;
            }
        }
    }
}

// ---------------------------------------------------------------------------
// Small-M sums GEMM with glds staging: part[ks][64][N] = A(64xK)@W(NxK).T
// ---------------------------------------------------------------------------
__global__ __launch_bounds__(256)
void gemm_sums_kernel(const unsigned short* __restrict__ A, int lda,
                      const unsigned short* __restrict__ W, int ldw,
                      float* __restrict__ part, int N, int Kblk)
{
    __shared__ __align__(16) unsigned short sA[64 * 32];
    __shared__ __align__(16) unsigned short sW[64 * 32];
    const int tid = threadIdx.x;
    const int n0 = blockIdx.x * 64;
    const int ks = blockIdx.y;
    const int kbeg = ks * Kblk;
    const int wave = tid >> 6, lane = tid & 63;
    const int lrow = lane & 15, lkg = lane >> 4;
    const int rsub   = lane >> 2;
    const int cchunk = (lane & 3) * 8;

    f32x4 acc[4];
    #pragma unroll
    for (int mi = 0; mi < 4; ++mi) acc[mi] = (f32x4){0.f, 0.f, 0.f, 0.f};

    for (int k0 = kbeg; k0 < kbeg + Kblk; k0 += 32) {
        __builtin_amdgcn_global_load_lds(
            GLB_PTR(A + (size_t)(wave * 16 + rsub) * lda + k0 + cchunk),
            LDS_PTR(sA + wave * 512), 16, 0, 0);
        __builtin_amdgcn_global_load_lds(
            GLB_PTR(W + (size_t)(n0 + wave * 16 + rsub) * ldw + k0 + cchunk),
            LDS_PTR(sW + wave * 512), 16, 0, 0);
        __syncthreads();
        const short8 wf = *(const short8*)(sW + (wave * 16 + lrow) * 32 + lkg * 8);
        #pragma unroll
        for (int mi = 0; mi < 4; ++mi) {
            const short8 af = *(const short8*)(sA + (mi * 16 + lrow) * 32 + lkg * 8);
            acc[mi] = __builtin_amdgcn_mfma_f32_16x16x32_bf16(af, wf, acc[mi], 0, 0, 0);
        }
        __syncthreads();
    }

    float* po = part + (size_t)ks * 64 * N;
    const int n = n0 + wave * 16 + lrow;
    #pragma unroll
    for (int mi = 0; mi < 4; ++mi)
        #pragma unroll
        for (int rr = 0; rr < 4; ++rr)
            po[(size_t)(mi * 16 + lkg * 4 + rr) * N + n] = acc[mi][rr];
}

// ---------------------------------------------------------------------------
// Step kernel (512 thr): e + softmax + l-split paired readout + gates.
// grid (4 fc, 64 b). Thread pair (tid>>1) owns r = fc*256 + (tid>>1);
// tid&1 selects l-half [0,98)/[98,196); shfl_xor(1) combines.
// comb layout: row stride kNc2; cols 0-511 = p_att, 512+ = pre_a2c(+bias).
// ---------------------------------------------------------------------------
__global__ __launch_bounds__(512)
void att_step_kernel(const float* __restrict__ part56,
                     const float* __restrict__ h2att_b,
                     const unsigned short* __restrict__ comb_bf,
                     const float* __restrict__ alpha_w,
                     const unsigned short* __restrict__ i2h_pre_bf,
                     const float* __restrict__ h2h_b,
                     float* __restrict__ cbuf,
                     unsigned short* __restrict__ h_all_bf,
                     int t)
{
    const int fc = blockIdx.x, b = blockIdx.y;
    const int tid = threadIdx.x;
    const int wave = tid >> 6, lane = tid & 63;
    __shared__ float ahT[8][64];
    __shared__ float awT[8][64];
    __shared__ float esm[kL];
    __shared__ float wsm[kL];
    __shared__ float red2[2];

    if (tid < kH) {
        const size_t base = (size_t)b * kNcat + 5 * kR + tid;
        float v = h2att_b[tid];
        #pragma unroll
        for (int s = 0; s < kKS; ++s) v += part56[(size_t)s * 64 * kNcat + base];
        ahT[tid & 7][tid >> 3] = v;
        awT[tid & 7][tid >> 3] = alpha_w[tid];
    }
    __syncthreads();

    // e: 8 waves, wave handles l = wave, wave+8, ...
    for (int l = wave; l < kL; l += 8) {
        const short8 pv = *(const short8*)(comb_bf + ((size_t)b * kL + l) * kNc2 + lane * 8);
        float a = 0.f;
        #pragma unroll
        for (int j = 0; j < 8; ++j)
            a += fast_tanh(bf2f(((const unsigned short*)&pv)[j]) + ahT[j][lane]) * awT[j][lane];
        #pragma unroll
        for (int off = 32; off; off >>= 1) a += __shfl_xor(a, off, 64);
        if (lane == 0) esm[l] = a;
    }
    __syncthreads();

    if (wave == 0) {
        float m = -1e30f;
        for (int l = lane; l < kL; l += 64) m = fmaxf(m, esm[l]);
        #pragma unroll
        for (int off = 32; off; off >>= 1) m = fmaxf(m, __shfl_xor(m, off, 64));
        float ssum = 0.f;
        for (int l = lane; l < kL; l += 64) ssum += __expf(esm[l] - m);
        #pragma unroll
        for (int off = 32; off; off >>= 1) ssum += __shfl_xor(ssum, off, 64);
        if (lane == 0) { red2[0] = m; red2[1] = 1.f / ssum; }
    }
    __syncthreads();
    if (tid < kL) wsm[tid] = __expf(esm[tid] - red2[0]) * red2[1];
    __syncthreads();

    // l-split paired readout: itr cols (512+r, 512+kR+r) of comb
    const int r = fc * 256 + (tid >> 1);
    const int l0 = (tid & 1) * 98;
    float s3 = 0.f, s4 = 0.f;
    const unsigned short* base = comb_bf + ((size_t)b * kL + l0) * kNc2 + kH + r;
    #pragma unroll 7
    for (int li = 0; li < 98; ++li) {
        const float wl = wsm[l0 + li];
        s3 += wl * bf2f(base[(size_t)li * kNc2]);
        s4 += wl * bf2f(base[(size_t)li * kNc2 + kR]);
    }
    s3 += __shfl_xor(s3, 1, 64);
    s4 += __shfl_xor(s4, 1, 64);

    if ((tid & 1) == 0) {
        const unsigned short* ib = i2h_pre_bf + (size_t)(b * kT + t) * (5 * kR);
        float S0 = bf2f(ib[r])          + h2h_b[r];
        float S1 = bf2f(ib[kR + r])     + h2h_b[kR + r];
        float S2 = bf2f(ib[2 * kR + r]) + h2h_b[2 * kR + r];
        float S3 = bf2f(ib[3 * kR + r]) + h2h_b[3 * kR + r] + s3;
        float S4 = bf2f(ib[4 * kR + r]) + h2h_b[4 * kR + r] + s4;
        #pragma unroll
        for (int s = 0; s < kKS; ++s) {
            const float* p = part56 + (size_t)s * 64 * kNcat + (size_t)b * kNcat;
            S0 += p[r];
            S1 += p[kR + r];
            S2 += p[2 * kR + r];
            S3 += p[3 * kR + r];
            S4 += p[4 * kR + r];
        }

        const float ing = fast_sig(S0);
        const float fg  = fast_sig(S1);
        const float og  = fast_sig(S2);
        const float gg  = fmaxf(S3, S4);
        const int idx = b * kR + r;
        const float nc = fg * cbuf[idx] + ing * gg;
        const float nh = og * fast_tanh(nc);
        cbuf[idx] = nc;
        h_all_bf[(size_t)(b * kT + t) * kR + r] = f2bf(nh);
    }
}

// ---------------------------------------------------------------------------
// in-place log_softmax over V; one block per row. Online max/sum.
// ---------------------------------------------------------------------------
__global__ __launch_bounds__(256)
void log_softmax_kernel(float* __restrict__ out)
{
    __shared__ float mred[256];
    __shared__ float sred[256];
    const int tid = threadIdx.x;
    float* row = out + (size_t)blockIdx.x * kV;

    float m = -1e30f, s = 0.f;
    for (int v = tid; v < kV; v += 256) {
        const float x = row[v];
        if (x > m) { s = s * __expf(m - x) + 1.f; m = x; }
        else        s += __expf(x - m);
    }
    mred[tid] = m; sred[tid] = s; __syncthreads();
    for (int st = 128; st > 0; st >>= 1) {
        if (tid < st) {
            const float m2 = mred[tid + st], s2 = sred[tid + st];
            const float M = fmaxf(mred[tid], m2);
            sred[tid] = sred[tid] * __expf(mred[tid] - M) + s2 * __expf(m2 - M);
            mred[tid] = M;
        }
        __syncthreads();
    }
    const float ls = mred[0] + logf(sred[0]);
    for (int v = tid; v < kV; v += 256) row[v] -= ls;
}

extern "C" void kernel_launch(void* const* d_in, const int* in_sizes, int n_in,
                              void* d_out, int out_size, void* d_ws, size_t ws_size,
                              hipStream_t stream)
{
    const int*   seq       = (const int*)  d_in[0];
    const float* att_feats = (const float*)d_in[1];
    const float* embed_w   = (const float*)d_in[2];
    const float* ctx2att_w = (const float*)d_in[3];
    const float* ctx2att_b = (const float*)d_in[4];
    const float* h2att_w   = (const float*)d_in[5];
    const float* h2att_b   = (const float*)d_in[6];
    const float* alpha_w   = (const float*)d_in[7];
    const float* i2h_w     = (const float*)d_in[9];
    const float* i2h_b     = (const float*)d_in[10];
    const float* h2h_w     = (const float*)d_in[11];
    const float* h2h_b     = (const float*)d_in[12];
    const float* a2c_w     = (const float*)d_in[13];
    const float* a2c_b     = (const float*)d_in[14];
    const float* logit_w   = (const float*)d_in[15];
    const float* logit_b   = (const float*)d_in[16];
    float* out = (float*)d_out;

    float* ws = (float*)d_ws;
    size_t off = 0;
    auto alloc = [&](size_t nf) { float* p = ws + off; off += (nf + 3) & ~(size_t)3; return p; };

    unsigned short* af_bf      = (unsigned short*)alloc((size_t)kB * kL * kF / 2);   // 51 MB
    unsigned short* comb_bf    = (unsigned short*)alloc((size_t)kB * kL * kNc2 / 2); // 61.6 MB
    unsigned short* logit_hi   = (unsigned short*)alloc((size_t)kV * kR / 2);
    unsigned short* embed_bf   = (unsigned short*)alloc((size_t)kV * kEp / 2);
    unsigned short* i2h_bf     = (unsigned short*)alloc((size_t)5 * kR * kEp / 2);
    unsigned short* wcat_bf    = (unsigned short*)alloc((size_t)kNcat * kR / 2);     // 11.5 MB
    unsigned short* wcomb_bf   = (unsigned short*)alloc((size_t)kNc2 * kF / 2);      // 10.5 MB
    unsigned short* h_all_bf   = (unsigned short*)alloc((size_t)kB * kT * kR / 2);
    unsigned short* h_zero_bf  = (unsigned short*)alloc((size_t)kB * kR / 2);
    unsigned short* i2h_pre_bf = (unsigned short*)alloc((size_t)kB * kT * 5 * kR / 2); // 13 MB
    float* bias_comb = alloc((size_t)kNc2);
    float* part56    = alloc((size_t)kKS * kB * kNcat);  // 5.8 MB
    float* cbuf      = alloc((size_t)kB * kR);

    // all conversions + packs + zero-fills in ONE launch
    conv_all_kernel<<<4096, 256, 0, stream>>>(
        att_feats, af_bf, ctx2att_w, logit_w, logit_hi,
        h2h_w, wcat_bf, h2att_w, wcat_bf + (size_t)5 * kR * kR,
        a2c_w, wcomb_bf, embed_w, embed_bf, i2h_w, i2h_bf,
        h_zero_bf, cbuf, ctx2att_b, a2c_b, bias_comb);

    // comb = att_feats @ [ctx2att | a2c].T + bias_comb -> bf16 (12544 x 2560, K=2048)
    gemm_glds_kernel<true, false><<<dim3(20 * 98), 256, 0, stream>>>(
        af_bf, kF, wcomb_bf, kF, bias_comb, comb_bf, kNc2, kB * kL, kNc2, kF, nullptr,
        20, 98, 1);

    // i2h_pre = embed[seq] @ i2h_w.T + b -> bf16   (1280 x 5120, K=320 padded)
    gemm_glds_kernel<true, true><<<dim3(40 * 10), 256, 0, stream>>>(
        embed_bf, kEp, i2h_bf, kEp, i2h_b, i2h_pre_bf, 5 * kR, kB * kT, 5 * kR, kEp, seq,
        40, 10, 1);

    // 20-step recurrence: 2 launches per step
    for (int t = 0; t < kT; ++t) {
        const unsigned short* h_prev = (t == 0) ? h_zero_bf : (h_all_bf + (size_t)(t - 1) * kR);
        const int lda_h = (t == 0) ? kR : kT * kR;

        // part56 = h_prev @ [h2h | h2att].T   (64 x 5632, K=1024, ks=4)
        gemm_sums_kernel<<<dim3(kNcat / 64, kKS), 256, 0, stream>>>(
            h_prev, lda_h, wcat_bf, kR, part56, kNcat, kR / kKS);

        att_step_kernel<<<dim3(4, kB), 512, 0, stream>>>(
            part56, h2att_b, comb_bf, alpha_w, i2h_pre_bf, h2h_b,
            cbuf, h_all_bf, t);
    }

    // logits = h_all @ logit_w.T + b -> out fp32  (1280 x 12001, K=1024)
    gemm_glds_kernel<false, false><<<dim3(94 * 10), 256, 0, stream>>>(
        h_all_bf, kR, logit_hi, kR, logit_b, out, kV, kB * kT, kV, kR, nullptr,
        94, 10, 0);

    log_softmax_kernel<<<dim3(kB * kT), 256, 0, stream>>>(out);
}

// Round 17
// 1178.366 us; speedup vs baseline: 3.2169x; 1.0591x over previous
//
#include <hip/hip_runtime.h>
#include <math.h>

namespace {
constexpr int kV = 12001;
constexpr int kE = 300;
constexpr int kEp = 320;   // padded K for i2h
constexpr int kR = 1024;
constexpr int kH = 512;
constexpr int kF = 2048;
constexpr int kB = 64;
constexpr int kT = 20;
constexpr int kL = 196;
constexpr int kNcat = 5 * kR + kH;   // 5632: [h2h | h2att]
constexpr int kKS = 4;               // K-split for gemm_sums
constexpr int kNc2 = kH + kF;        // 2560: [p_att | itr-interleaved] cols
}

typedef __attribute__((ext_vector_type(8))) short short8;
typedef __attribute__((ext_vector_type(4))) float f32x4;

#define GLB_PTR(p) ((const __attribute__((address_space(1))) void*)(p))
#define LDS_PTR(p) ((__attribute__((address_space(3))) void*)(p))

__device__ __forceinline__ unsigned short f2bf(float f) {
    unsigned u = __builtin_bit_cast(unsigned, f);
    u = (u + 0x7fffu + ((u >> 16) & 1u)) >> 16;
    return (unsigned short)u;
}
__device__ __forceinline__ float bf2f(unsigned short h) {
    unsigned u = ((unsigned)h) << 16;
    return __builtin_bit_cast(float, u);
}
__device__ __forceinline__ float fast_tanh(float x) {
    x = fminf(15.f, fmaxf(-15.f, x));
    const float e = __expf(2.f * x);
    return (e - 1.f) / (e + 1.f);
}
__device__ __forceinline__ float fast_sig(float x) {
    return 1.f / (1.f + __expf(-x));
}

// bijective XCD-chunk swizzle (m204)
__device__ __forceinline__ int xcd_swizzle(int orig, int nwg) {
    const int q = nwg >> 3, r = nwg & 7;
    const int xcd = orig & 7, lo = orig >> 3;
    return (xcd < r ? xcd * (q + 1) : r * (q + 1) + (xcd - r) * q) + lo;
}

// ---------------------------------------------------------------------------
// One-shot conversion/pack/zero kernel.
// wcomb rows: 0-511 = ctx2att; 512+2r = a2c gate3 row r; 512+2r+1 = gate4 row r.
// bias_comb packed to match.
// ---------------------------------------------------------------------------
__global__ __launch_bounds__(256)
void conv_all_kernel(const float* __restrict__ af_in,  unsigned short* __restrict__ af_out,
                     const float* __restrict__ ctx_in,
                     const float* __restrict__ lg_in,  unsigned short* __restrict__ lg_out,
                     const float* __restrict__ h2h_in, unsigned short* __restrict__ h2h_out,
                     const float* __restrict__ h2a_in, unsigned short* __restrict__ h2a_out,
                     const float* __restrict__ a2c_in, unsigned short* __restrict__ wcomb_out,
                     const float* __restrict__ emb_in, unsigned short* __restrict__ emb_out,
                     const float* __restrict__ i2h_in, unsigned short* __restrict__ i2h_out,
                     unsigned short* __restrict__ hz_out, float* __restrict__ cb_out,
                     const float* __restrict__ ctxb_in, const float* __restrict__ a2cb_in,
                     float* __restrict__ biasc_out)
{
    constexpr int c0 = kB * kL * kF / 4;                 // af
    constexpr int c1 = c0 + kH * kF / 4;                 // ctx -> wcomb rows 0-511
    constexpr int c2 = c1 + kV * kR / 4;                 // logit
    constexpr int c3 = c2 + 5 * kR * kR / 4;             // h2h -> wcat
    constexpr int c4 = c3 + kH * kR / 4;                 // h2att -> wcat tail
    constexpr int c5 = c4 + 2 * kR * kF / 4;             // a2c -> wcomb interleaved
    constexpr int c6 = c5 + kV * 80;                     // embed pad
    constexpr int c7 = c6 + 5 * kR * 80;                 // i2h pad
    constexpr int c8 = c7 + kB * kR / 4;                 // h_zero
    constexpr int c9 = c8 + kB * kR / 4;                 // cbuf zero
    constexpr int c10 = c9 + kNc2 / 4;                   // bias_comb

    for (int i = blockIdx.x * 256 + threadIdx.x; i < c10; i += gridDim.x * 256) {
        if (i < c4) {
            const float* in; unsigned short* out; int l;
            if      (i < c0) { in = af_in;  out = af_out;    l = i; }
            else if (i < c1) { in = ctx_in; out = wcomb_out; l = i - c0; }
            else if (i < c2) { in = lg_in;  out = lg_out;    l = i - c1; }
            else if (i < c3) { in = h2h_in; out = h2h_out;   l = i - c2; }
            else             { in = h2a_in; out = h2a_out;   l = i - c3; }
            const float4 v = ((const float4*)in)[l];
            ushort4 o;
            o.x = f2bf(v.x); o.y = f2bf(v.y); o.z = f2bf(v.z); o.w = f2bf(v.w);
            ((ushort4*)out)[l] = o;
        } else if (i < c5) {
            // a2c row q -> wcomb row 512 + (q<kR ? 2q : 2(q-kR)+1)
            const int l = i - c4;
            const int q = l >> 9;                 // row (kF/4 = 512 groups)
            const int g = l & 511;                // col group
            const int irow = (q < kR) ? (kH + 2 * q) : (kH + 2 * (q - kR) + 1);
            const float4 v = ((const float4*)a2c_in)[l];
            ushort4 o;
            o.x = f2bf(v.x); o.y = f2bf(v.y); o.z = f2bf(v.z); o.w = f2bf(v.w);
            ((ushort4*)wcomb_out)[(size_t)irow * (kF / 4) + g] = o;
        } else if (i < c7) {
            const float* in; unsigned short* out; int l;
            if (i < c6) { in = emb_in; out = emb_out; l = i - c5; }
            else        { in = i2h_in; out = i2h_out; l = i - c6; }
            const int row = l / 80, c = l - row * 80;
            ushort4 o = make_ushort4(0, 0, 0, 0);
            if (c < 75) {
                const float4 v = *(const float4*)(in + (size_t)row * kE + c * 4);
                o.x = f2bf(v.x); o.y = f2bf(v.y); o.z = f2bf(v.z); o.w = f2bf(v.w);
            }
            *(ushort4*)(out + (size_t)row * kEp + c * 4) = o;
        } else if (i < c8) {
            ((ushort4*)hz_out)[i - c7] = make_ushort4(0, 0, 0, 0);
        } else if (i < c9) {
            ((float4*)cb_out)[i - c8] = make_float4(0.f, 0.f, 0.f, 0.f);
        } else {
            const int l = i - c9;   // float4 group of bias_comb (640 groups)
            float4 v;
            if (l < kH / 4) {
                v = ((const float4*)ctxb_in)[l];
            } else {
                const int j0 = (l - kH / 4) * 4;   // 0.. within interleaved 2048
                float t[4];
                #pragma unroll
                for (int p = 0; p < 4; ++p) {
                    const int j = j0 + p;
                    const int r = j >> 1;
                    t[p] = a2cb_in[(j & 1) * kR + r];
                }
                v = make_float4(t[0], t[1], t[2], t[3]);
            }
            ((float4*)biasc_out)[l] = v;
        }
    }
}

// ---------------------------------------------------------------------------
// Pure-bf16 MFMA GEMM, width-16 global_load_lds staging, XCD-swizzled 1D grid.
// ---------------------------------------------------------------------------
template<bool OUT_BF16, bool GATHER>
__global__ __launch_bounds__(256)
void gemm_glds_kernel(const unsigned short* __restrict__ Ah, int lda,
                      const unsigned short* __restrict__ Wh, int ldw,
                      const float* __restrict__ bias,
                      void* __restrict__ Cp, int ldc,
                      int M, int N, int K,
                      const int* __restrict__ ridx,
                      int nbx, int nby, int nfirst)
{
    __shared__ __align__(16) unsigned short sA[128 * 32];
    __shared__ __align__(16) unsigned short sW[128 * 32];
    const int tid = threadIdx.x;
    const int swz = xcd_swizzle(blockIdx.x, nbx * nby);
    int bx, by;
    if (nfirst) { bx = swz % nbx; by = swz / nbx; }
    else        { by = swz % nby; bx = swz / nby; }
    const int m0 = by * 128;
    const int n0 = bx * 128;
    const int wave = tid >> 6, lane = tid & 63;
    const int wm = wave >> 1, wn = wave & 1;
    const int lrow = lane & 15, lkg = lane >> 4;

    const int rsub   = lane >> 2;
    const int cchunk = (lane & 3) * 8;

    f32x4 acc[4][4];
    #pragma unroll
    for (int mi = 0; mi < 4; ++mi)
        #pragma unroll
        for (int ni = 0; ni < 4; ++ni)
            acc[mi][ni] = (f32x4){0.f, 0.f, 0.f, 0.f};

    for (int k0 = 0; k0 < K; k0 += 32) {
        #pragma unroll
        for (int j = 0; j < 2; ++j) {
            const int mrow = m0 + wave * 32 + j * 16 + rsub;
            const int row = GATHER ? ridx[mrow] : mrow;
            __builtin_amdgcn_global_load_lds(
                GLB_PTR(Ah + (size_t)row * lda + k0 + cchunk),
                LDS_PTR(sA + wave * 1024 + j * 512), 16, 0, 0);
        }
        #pragma unroll
        for (int j = 0; j < 2; ++j) {
            const int n = n0 + wave * 32 + j * 16 + rsub;
            __builtin_amdgcn_global_load_lds(
                GLB_PTR(Wh + (size_t)n * ldw + k0 + cchunk),
                LDS_PTR(sW + wave * 1024 + j * 512), 16, 0, 0);
        }
        __syncthreads();

        short8 af[4], wf[4];
        #pragma unroll
        for (int mi = 0; mi < 4; ++mi)
            af[mi] = *(const short8*)(sA + (wm * 64 + mi * 16 + lrow) * 32 + lkg * 8);
        #pragma unroll
        for (int ni = 0; ni < 4; ++ni)
            wf[ni] = *(const short8*)(sW + (wn * 64 + ni * 16 + lrow) * 32 + lkg * 8);
        #pragma unroll
        for (int mi = 0; mi < 4; ++mi)
            #pragma unroll
            for (int ni = 0; ni < 4; ++ni)
                acc[mi][ni] = __builtin_amdgcn_mfma_f32_16x16x32_bf16(af[mi], wf[ni], acc[mi][ni], 0, 0, 0);
        __syncthreads();
    }

    // epilogue: row = (lane>>4)*4 + reg, col = lane&15 (m89-verified layout)
    #pragma unroll
    for (int mi = 0; mi < 4; ++mi) {
        const int mbase = m0 + wm * 64 + mi * 16 + lkg * 4;
        #pragma unroll
        for (int ni = 0; ni < 4; ++ni) {
            const int n = n0 + wn * 64 + ni * 16 + lrow;
            if (n >= N) continue;
            const float bb = bias ? bias[n] : 0.f;
            #pragma unroll
            for (int r = 0; r < 4; ++r) {
                const int m = mbase + r;
                const float v = acc[mi][ni][r] + bb;
                if (OUT_BF16) ((unsigned short*)Cp)[(size_t)m * ldc + n] = f2bf(v);
                else          ((float*)Cp)[(size_t)m * ldc + n] = v;
            }
        }
    }
}

// ---------------------------------------------------------------------------
// Small-M sums GEMM with glds staging: part[ks][64][N] = A(64xK)@W(NxK).T
// ---------------------------------------------------------------------------
__global__ __launch_bounds__(256)
void gemm_sums_kernel(const unsigned short* __restrict__ A, int lda,
                      const unsigned short* __restrict__ W, int ldw,
                      float* __restrict__ part, int N, int Kblk)
{
    __shared__ __align__(16) unsigned short sA[64 * 32];
    __shared__ __align__(16) unsigned short sW[64 * 32];
    const int tid = threadIdx.x;
    const int n0 = blockIdx.x * 64;
    const int ks = blockIdx.y;
    const int kbeg = ks * Kblk;
    const int wave = tid >> 6, lane = tid & 63;
    const int lrow = lane & 15, lkg = lane >> 4;
    const int rsub   = lane >> 2;
    const int cchunk = (lane & 3) * 8;

    f32x4 acc[4];
    #pragma unroll
    for (int mi = 0; mi < 4; ++mi) acc[mi] = (f32x4){0.f, 0.f, 0.f, 0.f};

    for (int k0 = kbeg; k0 < kbeg + Kblk; k0 += 32) {
        __builtin_amdgcn_global_load_lds(
            GLB_PTR(A + (size_t)(wave * 16 + rsub) * lda + k0 + cchunk),
            LDS_PTR(sA + wave * 512), 16, 0, 0);
        __builtin_amdgcn_global_load_lds(
            GLB_PTR(W + (size_t)(n0 + wave * 16 + rsub) * ldw + k0 + cchunk),
            LDS_PTR(sW + wave * 512), 16, 0, 0);
        __syncthreads();
        const short8 wf = *(const short8*)(sW + (wave * 16 + lrow) * 32 + lkg * 8);
        #pragma unroll
        for (int mi = 0; mi < 4; ++mi) {
            const short8 af = *(const short8*)(sA + (mi * 16 + lrow) * 32 + lkg * 8);
            acc[mi] = __builtin_amdgcn_mfma_f32_16x16x32_bf16(af, wf, acc[mi], 0, 0, 0);
        }
        __syncthreads();
    }

    float* po = part + (size_t)ks * 64 * N;
    const int n = n0 + wave * 16 + lrow;
    #pragma unroll
    for (int mi = 0; mi < 4; ++mi)
        #pragma unroll
        for (int rr = 0; rr < 4; ++rr)
            po[(size_t)(mi * 16 + lkg * 4 + rr) * N + n] = acc[mi][rr];
}

// ---------------------------------------------------------------------------
// Step kernel (512 thr): e + softmax + l-split INTERLEAVED readout + gates.
// grid (4 fc, 64 b). Thread pair (tid>>1) owns r; tid&1 = l-half.
// comb cols: 0-511 p_att; 512+2r = itr gate3 col r; 512+2r+1 = gate4 col r.
// ---------------------------------------------------------------------------
__global__ __launch_bounds__(512)
void att_step_kernel(const float* __restrict__ part56,
                     const float* __restrict__ h2att_b,
                     const unsigned short* __restrict__ comb_bf,
                     const float* __restrict__ alpha_w,
                     const unsigned short* __restrict__ i2h_pre_bf,
                     const float* __restrict__ h2h_b,
                     float* __restrict__ cbuf,
                     unsigned short* __restrict__ h_all_bf,
                     int t)
{
    const int fc = blockIdx.x, b = blockIdx.y;
    const int tid = threadIdx.x;
    const int wave = tid >> 6, lane = tid & 63;
    __shared__ float ahT[8][64];
    __shared__ float awT[8][64];
    __shared__ float esm[kL];
    __shared__ float wsm[kL];
    __shared__ float red2[2];

    if (tid < kH) {
        const size_t base = (size_t)b * kNcat + 5 * kR + tid;
        float v = h2att_b[tid];
        #pragma unroll
        for (int s = 0; s < kKS; ++s) v += part56[(size_t)s * 64 * kNcat + base];
        ahT[tid & 7][tid >> 3] = v;
        awT[tid & 7][tid >> 3] = alpha_w[tid];
    }
    __syncthreads();

    // e: 8 waves, wave handles l = wave, wave+8, ...
    for (int l = wave; l < kL; l += 8) {
        const short8 pv = *(const short8*)(comb_bf + ((size_t)b * kL + l) * kNc2 + lane * 8);
        float a = 0.f;
        #pragma unroll
        for (int j = 0; j < 8; ++j)
            a += fast_tanh(bf2f(((const unsigned short*)&pv)[j]) + ahT[j][lane]) * awT[j][lane];
        #pragma unroll
        for (int off = 32; off; off >>= 1) a += __shfl_xor(a, off, 64);
        if (lane == 0) esm[l] = a;
    }
    __syncthreads();

    if (wave == 0) {
        float m = -1e30f;
        for (int l = lane; l < kL; l += 64) m = fmaxf(m, esm[l]);
        #pragma unroll
        for (int off = 32; off; off >>= 1) m = fmaxf(m, __shfl_xor(m, off, 64));
        float ssum = 0.f;
        for (int l = lane; l < kL; l += 64) ssum += __expf(esm[l] - m);
        #pragma unroll
        for (int off = 32; off; off >>= 1) ssum += __shfl_xor(ssum, off, 64);
        if (lane == 0) { red2[0] = m; red2[1] = 1.f / ssum; }
    }
    __syncthreads();
    if (tid < kL) wsm[tid] = __expf(esm[tid] - red2[0]) * red2[1];
    __syncthreads();

    // l-split interleaved readout: one ushort2 per l = (gate3, gate4)
    const int r = fc * 256 + (tid >> 1);
    const int l0 = (tid & 1) * 98;
    float s3 = 0.f, s4 = 0.f;
    const unsigned short* base = comb_bf + ((size_t)b * kL + l0) * kNc2 + kH + 2 * r;
    #pragma unroll 7
    for (int li = 0; li < 98; ++li) {
        const ushort2 v = *(const ushort2*)(base + (size_t)li * kNc2);
        const float wl = wsm[l0 + li];
        s3 += wl * bf2f(v.x);
        s4 += wl * bf2f(v.y);
    }
    s3 += __shfl_xor(s3, 1, 64);
    s4 += __shfl_xor(s4, 1, 64);

    if ((tid & 1) == 0) {
        const unsigned short* ib = i2h_pre_bf + (size_t)(b * kT + t) * (5 * kR);
        float S0 = bf2f(ib[r])          + h2h_b[r];
        float S1 = bf2f(ib[kR + r])     + h2h_b[kR + r];
        float S2 = bf2f(ib[2 * kR + r]) + h2h_b[2 * kR + r];
        float S3 = bf2f(ib[3 * kR + r]) + h2h_b[3 * kR + r] + s3;
        float S4 = bf2f(ib[4 * kR + r]) + h2h_b[4 * kR + r] + s4;
        #pragma unroll
        for (int s = 0; s < kKS; ++s) {
            const float* p = part56 + (size_t)s * 64 * kNcat + (size_t)b * kNcat;
            S0 += p[r];
            S1 += p[kR + r];
            S2 += p[2 * kR + r];
            S3 += p[3 * kR + r];
            S4 += p[4 * kR + r];
        }

        const float ing = fast_sig(S0);
        const float fg  = fast_sig(S1);
        const float og  = fast_sig(S2);
        const float gg  = fmaxf(S3, S4);
        const int idx = b * kR + r;
        const float nc = fg * cbuf[idx] + ing * gg;
        const float nh = og * fast_tanh(nc);
        cbuf[idx] = nc;
        h_all_bf[(size_t)(b * kT + t) * kR + r] = f2bf(nh);
    }
}

// ---------------------------------------------------------------------------
// in-place log_softmax over V; one block per row. Online max/sum.
// ---------------------------------------------------------------------------
__global__ __launch_bounds__(256)
void log_softmax_kernel(float* __restrict__ out)
{
    __shared__ float mred[256];
    __shared__ float sred[256];
    const int tid = threadIdx.x;
    float* row = out + (size_t)blockIdx.x * kV;

    float m = -1e30f, s = 0.f;
    for (int v = tid; v < kV; v += 256) {
        const float x = row[v];
        if (x > m) { s = s * __expf(m - x) + 1.f; m = x; }
        else        s += __expf(x - m);
    }
    mred[tid] = m; sred[tid] = s; __syncthreads();
    for (int st = 128; st > 0; st >>= 1) {
        if (tid < st) {
            const float m2 = mred[tid + st], s2 = sred[tid + st];
            const float M = fmaxf(mred[tid], m2);
            sred[tid] = sred[tid] * __expf(mred[tid] - M) + s2 * __expf(m2 - M);
            mred[tid] = M;
        }
        __syncthreads();
    }
    const float ls = mred[0] + logf(sred[0]);
    for (int v = tid; v < kV; v += 256) row[v] -= ls;
}

extern "C" void kernel_launch(void* const* d_in, const int* in_sizes, int n_in,
                              void* d_out, int out_size, void* d_ws, size_t ws_size,
                              hipStream_t stream)
{
    const int*   seq       = (const int*)  d_in[0];
    const float* att_feats = (const float*)d_in[1];
    const float* embed_w   = (const float*)d_in[2];
    const float* ctx2att_w = (const float*)d_in[3];
    const float* ctx2att_b = (const float*)d_in[4];
    const float* h2att_w   = (const float*)d_in[5];
    const float* h2att_b   = (const float*)d_in[6];
    const float* alpha_w   = (const float*)d_in[7];
    const float* i2h_w     = (const float*)d_in[9];
    const float* i2h_b     = (const float*)d_in[10];
    const float* h2h_w     = (const float*)d_in[11];
    const float* h2h_b     = (const float*)d_in[12];
    const float* a2c_w     = (const float*)d_in[13];
    const float* a2c_b     = (const float*)d_in[14];
    const float* logit_w   = (const float*)d_in[15];
    const float* logit_b   = (const float*)d_in[16];
    float* out = (float*)d_out;

    float* ws = (float*)d_ws;
    size_t off = 0;
    auto alloc = [&](size_t nf) { float* p = ws + off; off += (nf + 3) & ~(size_t)3; return p; };

    unsigned short* af_bf      = (unsigned short*)alloc((size_t)kB * kL * kF / 2);   // 51 MB
    unsigned short* comb_bf    = (unsigned short*)alloc((size_t)kB * kL * kNc2 / 2); // 61.6 MB
    unsigned short* logit_hi   = (unsigned short*)alloc((size_t)kV * kR / 2);
    unsigned short* embed_bf   = (unsigned short*)alloc((size_t)kV * kEp / 2);
    unsigned short* i2h_bf     = (unsigned short*)alloc((size_t)5 * kR * kEp / 2);
    unsigned short* wcat_bf    = (unsigned short*)alloc((size_t)kNcat * kR / 2);     // 11.5 MB
    unsigned short* wcomb_bf   = (unsigned short*)alloc((size_t)kNc2 * kF / 2);      // 10.5 MB
    unsigned short* h_all_bf   = (unsigned short*)alloc((size_t)kB * kT * kR / 2);
    unsigned short* h_zero_bf  = (unsigned short*)alloc((size_t)kB * kR / 2);
    unsigned short* i2h_pre_bf = (unsigned short*)alloc((size_t)kB * kT * 5 * kR / 2); // 13 MB
    float* bias_comb = alloc((size_t)kNc2);
    float* part56    = alloc((size_t)kKS * kB * kNcat);  // 5.8 MB
    float* cbuf      = alloc((size_t)kB * kR);

    // all conversions + packs + zero-fills in ONE launch
    conv_all_kernel<<<4096, 256, 0, stream>>>(
        att_feats, af_bf, ctx2att_w, logit_w, logit_hi,
        h2h_w, wcat_bf, h2att_w, wcat_bf + (size_t)5 * kR * kR,
        a2c_w, wcomb_bf, embed_w, embed_bf, i2h_w, i2h_bf,
        h_zero_bf, cbuf, ctx2att_b, a2c_b, bias_comb);

    // comb = att_feats @ [ctx2att | a2c-interleaved].T + bias_comb -> bf16
    gemm_glds_kernel<true, false><<<dim3(20 * 98), 256, 0, stream>>>(
        af_bf, kF, wcomb_bf, kF, bias_comb, comb_bf, kNc2, kB * kL, kNc2, kF, nullptr,
        20, 98, 1);

    // i2h_pre = embed[seq] @ i2h_w.T + b -> bf16   (1280 x 5120, K=320 padded)
    gemm_glds_kernel<true, true><<<dim3(40 * 10), 256, 0, stream>>>(
        embed_bf, kEp, i2h_bf, kEp, i2h_b, i2h_pre_bf, 5 * kR, kB * kT, 5 * kR, kEp, seq,
        40, 10, 1);

    // 20-step recurrence: 2 launches per step
    for (int t = 0; t < kT; ++t) {
        const unsigned short* h_prev = (t == 0) ? h_zero_bf : (h_all_bf + (size_t)(t - 1) * kR);
        const int lda_h = (t == 0) ? kR : kT * kR;

        // part56 = h_prev @ [h2h | h2att].T   (64 x 5632, K=1024, ks=4)
        gemm_sums_kernel<<<dim3(kNcat / 64, kKS), 256, 0, stream>>>(
            h_prev, lda_h, wcat_bf, kR, part56, kNcat, kR / kKS);

        att_step_kernel<<<dim3(4, kB), 512, 0, stream>>>(
            part56, h2att_b, comb_bf, alpha_w, i2h_pre_bf, h2h_b,
            cbuf, h_all_bf, t);
    }

    // logits = h_all @ logit_w.T + b -> out fp32  (1280 x 12001, K=1024)
    gemm_glds_kernel<false, false><<<dim3(94 * 10), 256, 0, stream>>>(
        h_all_bf, kR, logit_hi, kR, logit_b, out, kV, kB * kT, kV, kR, nullptr,
        94, 10, 0);

    log_softmax_kernel<<<dim3(kB * kT), 256, 0, stream>>>(out);
}